// Round 1
// baseline (1546.354 us; speedup 1.0000x reference)
//
#include <hip/hip_runtime.h>

#define NN 50000
#define NE 800000

// ---------------- CSR build ----------------

__global__ __launch_bounds__(256) void zero_int_kernel(int* __restrict__ p, int n) {
    int i = blockIdx.x * 256 + threadIdx.x;
    if (i < n) p[i] = 0;
}

__global__ __launch_bounds__(256) void count_deg_kernel(const int* __restrict__ dst,
                                                        int* __restrict__ deg) {
    int e = blockIdx.x * 256 + threadIdx.x;
    if (e < NE) atomicAdd(&deg[dst[e]], 1);
}

__global__ __launch_bounds__(256) void dinv_kernel(const int* __restrict__ deg,
                                                   float* __restrict__ dinv) {
    int v = blockIdx.x * 256 + threadIdx.x;
    if (v < NN) dinv[v] = rsqrtf((float)(deg[v] + 1));  // +1 self loop
}

// block-level exclusive scan of deg -> row_ptr (per-block), block totals -> blk
__global__ __launch_bounds__(256) void scan_blocks_kernel(const int* __restrict__ deg,
                                                          int* __restrict__ out,
                                                          int* __restrict__ blk, int n) {
    __shared__ int s[256];
    int tid = threadIdx.x;
    int i = blockIdx.x * 256 + tid;
    int v = (i < n) ? deg[i] : 0;
    s[tid] = v;
    __syncthreads();
    for (int off = 1; off < 256; off <<= 1) {
        int t = (tid >= off) ? s[tid - off] : 0;
        __syncthreads();
        s[tid] += t;
        __syncthreads();
    }
    if (i < n) out[i] = s[tid] - v;       // exclusive within block
    if (tid == 255) blk[blockIdx.x] = s[255];
}

// single block: exclusive scan of block sums in place; also write row_ptr[n]=total
__global__ __launch_bounds__(256) void scan_sums_kernel(int* __restrict__ blk, int nb,
                                                        int* __restrict__ row_ptr, int n) {
    __shared__ int s[256];
    int tid = threadIdx.x;
    int v = (tid < nb) ? blk[tid] : 0;
    s[tid] = v;
    __syncthreads();
    for (int off = 1; off < 256; off <<= 1) {
        int t = (tid >= off) ? s[tid - off] : 0;
        __syncthreads();
        s[tid] += t;
        __syncthreads();
    }
    if (tid < nb) blk[tid] = s[tid] - v;  // exclusive
    if (tid == 255) row_ptr[n] = s[255];  // grand total (== NE)
}

__global__ __launch_bounds__(256) void scan_add_kernel(int* __restrict__ row_ptr,
                                                       const int* __restrict__ blk,
                                                       int* __restrict__ cursor, int n) {
    int i = blockIdx.x * 256 + threadIdx.x;
    if (i < n) {
        int r = row_ptr[i] + blk[blockIdx.x];
        row_ptr[i] = r;
        cursor[i] = r;
    }
}

__global__ __launch_bounds__(256) void scatter_kernel(const int* __restrict__ src,
                                                      const int* __restrict__ dst,
                                                      int* __restrict__ cursor,
                                                      int* __restrict__ col_src) {
    int e = blockIdx.x * 256 + threadIdx.x;
    if (e < NE) {
        int d = dst[e];
        int pos = atomicAdd(&cursor[d], 1);
        col_src[pos] = src[e];
    }
}

// ---------------- aggregation: out[v] = dv*sum_{u->v} du*H[u] + dv^2*H[v] (+bias, relu) ----

// one wave per node, one float per lane (widths <= 64)
template <int WD, bool BIAS, bool RELU>
__global__ __launch_bounds__(256) void aggregate_scalar_kernel(
    const float* __restrict__ H, const float* __restrict__ dinv,
    const int* __restrict__ row_ptr, const int* __restrict__ col_src,
    const float* __restrict__ bias, float* __restrict__ out) {
    int v = blockIdx.x * 4 + (threadIdx.x >> 6);
    int lane = threadIdx.x & 63;
    if (v >= NN) return;
    bool act = lane < WD;
    float dv = dinv[v];
    int beg = row_ptr[v], end = row_ptr[v + 1];
    float self = act ? H[(size_t)v * WD + lane] : 0.0f;
    float acc = 0.0f;
    for (int e = beg; e < end; ++e) {
        int u = col_src[e];
        float du = dinv[u];
        float h = act ? H[(size_t)u * WD + lane] : 0.0f;
        acc += du * h;
    }
    float r = dv * acc + dv * dv * self;
    if (act) {
        if (BIAS) r += bias[lane];
        if (RELU) r = fmaxf(r, 0.0f);
        out[(size_t)v * WD + lane] = r;
    }
}

// one wave per node, one float4 per lane (width == 256)
template <bool BIAS, bool RELU>
__global__ __launch_bounds__(256) void aggregate_v4_256_kernel(
    const float* __restrict__ H, const float* __restrict__ dinv,
    const int* __restrict__ row_ptr, const int* __restrict__ col_src,
    const float* __restrict__ bias, float* __restrict__ out) {
    int v = blockIdx.x * 4 + (threadIdx.x >> 6);
    int lane = threadIdx.x & 63;
    if (v >= NN) return;
    const float4* Hv = (const float4*)H;
    float dv = dinv[v];
    int beg = row_ptr[v], end = row_ptr[v + 1];
    float4 self = Hv[(size_t)v * 64 + lane];
    float4 acc = make_float4(0.f, 0.f, 0.f, 0.f);
    for (int e = beg; e < end; ++e) {
        int u = col_src[e];
        float du = dinv[u];
        float4 h = Hv[(size_t)u * 64 + lane];
        acc.x += du * h.x;
        acc.y += du * h.y;
        acc.z += du * h.z;
        acc.w += du * h.w;
    }
    float dv2 = dv * dv;
    float4 r;
    r.x = dv * acc.x + dv2 * self.x;
    r.y = dv * acc.y + dv2 * self.y;
    r.z = dv * acc.z + dv2 * self.z;
    r.w = dv * acc.w + dv2 * self.w;
    if (BIAS) {
        float4 b = ((const float4*)bias)[lane];
        r.x += b.x; r.y += b.y; r.z += b.z; r.w += b.w;
    }
    if (RELU) {
        r.x = fmaxf(r.x, 0.f); r.y = fmaxf(r.y, 0.f);
        r.z = fmaxf(r.z, 0.f); r.w = fmaxf(r.w, 0.f);
    }
    ((float4*)out)[(size_t)v * 64 + lane] = r;
}

// ---------------- fp32 tiled GEMM: C[M,Nd] = A[M,K] @ W[K,Nd] (+bias, relu) -------------

template <bool BIASRELU>
__global__ __launch_bounds__(256) void gemm_kernel(const float* __restrict__ A,
                                                   const float* __restrict__ W,
                                                   const float* __restrict__ bias,
                                                   float* __restrict__ C,
                                                   int M, int K, int Nd) {
    const int BM = 64, BN = 64, BK = 16;
    __shared__ float As[BK][BM + 1];
    __shared__ float Ws[BK][BN + 1];
    int bm = blockIdx.y * BM;
    int bn = blockIdx.x * BN;
    int tid = threadIdx.x;
    int tx = tid & 15;   // 0..15 -> 4 cols each
    int ty = tid >> 4;   // 0..15 -> 4 rows each
    float acc[4][4];
#pragma unroll
    for (int i = 0; i < 4; ++i)
#pragma unroll
        for (int j = 0; j < 4; ++j) acc[i][j] = 0.0f;

    for (int k0 = 0; k0 < K; k0 += BK) {
        // A tile: 64 rows x 16 k
        int r = tid >> 2;
        int c = (tid & 3) * 4;
        int gm = bm + r;
#pragma unroll
        for (int i = 0; i < 4; ++i) {
            int gk = k0 + c + i;
            As[c + i][r] = (gm < M && gk < K) ? A[(size_t)gm * K + gk] : 0.0f;
        }
        // W tile: 16 k x 64 cols
        int n = tid & 63;
        int kk0 = (tid >> 6) * 4;
#pragma unroll
        for (int i = 0; i < 4; ++i) {
            int gk = k0 + kk0 + i;
            Ws[kk0 + i][n] = (gk < K && (bn + n) < Nd) ? W[(size_t)gk * Nd + bn + n] : 0.0f;
        }
        __syncthreads();
#pragma unroll
        for (int kk = 0; kk < BK; ++kk) {
            float a[4], b[4];
#pragma unroll
            for (int i = 0; i < 4; ++i) a[i] = As[kk][ty * 4 + i];
#pragma unroll
            for (int j = 0; j < 4; ++j) b[j] = Ws[kk][tx * 4 + j];
#pragma unroll
            for (int i = 0; i < 4; ++i)
#pragma unroll
                for (int j = 0; j < 4; ++j) acc[i][j] += a[i] * b[j];
        }
        __syncthreads();
    }
#pragma unroll
    for (int i = 0; i < 4; ++i) {
        int m = bm + ty * 4 + i;
        if (m >= M) continue;
#pragma unroll
        for (int j = 0; j < 4; ++j) {
            int nn = bn + tx * 4 + j;
            if (nn >= Nd) continue;
            float v = acc[i][j];
            if (BIASRELU) {
                v += bias[nn];
                v = fmaxf(v, 0.0f);
            }
            C[(size_t)m * Nd + nn] = v;
        }
    }
}

// ---------------- launch ----------------

extern "C" void kernel_launch(void* const* d_in, const int* in_sizes, int n_in,
                              void* d_out, int out_size, void* d_ws, size_t ws_size,
                              hipStream_t stream) {
    const float* x = (const float*)d_in[0];
    const int* ei = (const int*)d_in[1];
    const int* e_src = ei;
    const int* e_dst = ei + NE;
    const float* W1 = (const float*)d_in[2];
    const float* b1 = (const float*)d_in[3];
    const float* W2 = (const float*)d_in[4];
    const float* b2 = (const float*)d_in[5];
    const float* W3 = (const float*)d_in[6];
    const float* b3 = (const float*)d_in[7];
    const float* W4 = (const float*)d_in[8];
    const float* b4 = (const float*)d_in[9];
    const float* W5 = (const float*)d_in[10];
    const float* b5 = (const float*)d_in[11];
    const float* W6 = (const float*)d_in[12];
    const float* b6 = (const float*)d_in[13];
    float* out = (float*)d_out;

    // workspace layout
    float* bufA = (float*)d_ws;                       // N*512 f
    float* bufB = bufA + (size_t)NN * 512;            // N*512 f
    float* dinv = bufB + (size_t)NN * 512;            // N f
    int* deg = (int*)(dinv + NN);                     // N i
    int* row_ptr = deg + NN;                          // N+1 i
    int* cursor = row_ptr + NN + 1;                   // N i
    int* col_src = cursor + NN;                       // E i
    int* blk = col_src + NE;                          // 256 i

    const int nblkN = (NN + 255) / 256;   // 196
    const int nblkE = (NE + 255) / 256;   // 3125

    // CSR build
    zero_int_kernel<<<nblkN, 256, 0, stream>>>(deg, NN);
    count_deg_kernel<<<nblkE, 256, 0, stream>>>(e_dst, deg);
    dinv_kernel<<<nblkN, 256, 0, stream>>>(deg, dinv);
    scan_blocks_kernel<<<nblkN, 256, 0, stream>>>(deg, row_ptr, blk, NN);
    scan_sums_kernel<<<1, 256, 0, stream>>>(blk, nblkN, row_ptr, NN);
    scan_add_kernel<<<nblkN, 256, 0, stream>>>(row_ptr, blk, cursor, NN);
    scatter_kernel<<<nblkE, 256, 0, stream>>>(e_src, e_dst, cursor, col_src);

    const int aggGrid = (NN + 3) / 4;  // 12500, one wave per node

    // L1: AGG = S*x (35) -> bufA ; X1 = relu(bufA@W1+b1) -> bufB (64)
    aggregate_scalar_kernel<35, false, false><<<aggGrid, 256, 0, stream>>>(
        x, dinv, row_ptr, col_src, nullptr, bufA);
    {
        dim3 g((64 + 63) / 64, (NN + 63) / 64);
        gemm_kernel<true><<<g, 256, 0, stream>>>(bufA, W1, b1, bufB, NN, 35, 64);
    }
    // L2: AGG = S*X1 (64) -> bufA ; X2 = relu(bufA@W2+b2) -> bufB (256)
    aggregate_scalar_kernel<64, false, false><<<aggGrid, 256, 0, stream>>>(
        bufB, dinv, row_ptr, col_src, nullptr, bufA);
    {
        dim3 g((256 + 63) / 64, (NN + 63) / 64);
        gemm_kernel<true><<<g, 256, 0, stream>>>(bufA, W2, b2, bufB, NN, 64, 256);
    }
    // L3: AGG = S*X2 (256) -> bufA ; X3 = relu(bufA@W3+b3) -> bufB (512)
    aggregate_v4_256_kernel<false, false><<<aggGrid, 256, 0, stream>>>(
        bufB, dinv, row_ptr, col_src, nullptr, bufA);
    {
        dim3 g((512 + 63) / 64, (NN + 63) / 64);
        gemm_kernel<true><<<g, 256, 0, stream>>>(bufA, W3, b3, bufB, NN, 256, 512);
    }
    // L4: H = X3@W4 -> bufA (256) ; X4 = relu(S*bufA + b4) -> bufB (256)
    {
        dim3 g((256 + 63) / 64, (NN + 63) / 64);
        gemm_kernel<false><<<g, 256, 0, stream>>>(bufB, W4, nullptr, bufA, NN, 512, 256);
    }
    aggregate_v4_256_kernel<true, true><<<aggGrid, 256, 0, stream>>>(
        bufA, dinv, row_ptr, col_src, b4, bufB);
    // L5: H = X4@W5 -> bufA (64) ; X5 = relu(S*bufA + b5) -> bufB (64)
    {
        dim3 g((64 + 63) / 64, (NN + 63) / 64);
        gemm_kernel<false><<<g, 256, 0, stream>>>(bufB, W5, nullptr, bufA, NN, 256, 64);
    }
    aggregate_scalar_kernel<64, true, true><<<aggGrid, 256, 0, stream>>>(
        bufA, dinv, row_ptr, col_src, b5, bufB);
    // L6: H = X5@W6 -> bufA (16) ; OUT = S*bufA + b6 -> d_out (16)
    {
        dim3 g((16 + 63) / 64, (NN + 63) / 64);
        gemm_kernel<false><<<g, 256, 0, stream>>>(bufB, W6, nullptr, bufA, NN, 64, 16);
    }
    aggregate_scalar_kernel<16, true, false><<<aggGrid, 256, 0, stream>>>(
        bufA, dinv, row_ptr, col_src, b6, out);
}

// Round 2
// 959.451 us; speedup vs baseline: 1.6117x; 1.6117x over previous
//
#include <hip/hip_runtime.h>

#define NN 50000
#define NE 800000

// ---------------- CSR build ----------------

__global__ __launch_bounds__(256) void zero_int_kernel(int* __restrict__ p, int n) {
    int i = blockIdx.x * 256 + threadIdx.x;
    if (i < n) p[i] = 0;
}

__global__ __launch_bounds__(256) void count_deg_kernel(const int* __restrict__ dst,
                                                        int* __restrict__ deg) {
    int e = blockIdx.x * 256 + threadIdx.x;
    if (e < NE) atomicAdd(&deg[dst[e]], 1);
}

__global__ __launch_bounds__(256) void dinv_kernel(const int* __restrict__ deg,
                                                   float* __restrict__ dinv) {
    int v = blockIdx.x * 256 + threadIdx.x;
    if (v < NN) dinv[v] = rsqrtf((float)(deg[v] + 1));  // +1 self loop
}

__global__ __launch_bounds__(256) void scan_blocks_kernel(const int* __restrict__ deg,
                                                          int* __restrict__ out,
                                                          int* __restrict__ blk, int n) {
    __shared__ int s[256];
    int tid = threadIdx.x;
    int i = blockIdx.x * 256 + tid;
    int v = (i < n) ? deg[i] : 0;
    s[tid] = v;
    __syncthreads();
    for (int off = 1; off < 256; off <<= 1) {
        int t = (tid >= off) ? s[tid - off] : 0;
        __syncthreads();
        s[tid] += t;
        __syncthreads();
    }
    if (i < n) out[i] = s[tid] - v;
    if (tid == 255) blk[blockIdx.x] = s[255];
}

__global__ __launch_bounds__(256) void scan_sums_kernel(int* __restrict__ blk, int nb,
                                                        int* __restrict__ row_ptr, int n) {
    __shared__ int s[256];
    int tid = threadIdx.x;
    int v = (tid < nb) ? blk[tid] : 0;
    s[tid] = v;
    __syncthreads();
    for (int off = 1; off < 256; off <<= 1) {
        int t = (tid >= off) ? s[tid - off] : 0;
        __syncthreads();
        s[tid] += t;
        __syncthreads();
    }
    if (tid < nb) blk[tid] = s[tid] - v;
    if (tid == 255) row_ptr[n] = s[255];
}

__global__ __launch_bounds__(256) void scan_add_kernel(int* __restrict__ row_ptr,
                                                       const int* __restrict__ blk,
                                                       int* __restrict__ cursor, int n) {
    int i = blockIdx.x * 256 + threadIdx.x;
    if (i < n) {
        int r = row_ptr[i] + blk[blockIdx.x];
        row_ptr[i] = r;
        cursor[i] = r;
    }
}

__global__ __launch_bounds__(256) void scatter_kernel(const int* __restrict__ src,
                                                      const int* __restrict__ dst,
                                                      int* __restrict__ cursor,
                                                      int* __restrict__ col_src) {
    int e = blockIdx.x * 256 + threadIdx.x;
    if (e < NE) {
        int d = dst[e];
        int pos = atomicAdd(&cursor[d], 1);
        col_src[pos] = src[e];
    }
}

// ------- aggregation: out[v] = dv*sum du*H[u] + dv^2*H[v] (+bias,relu) -------
// GS lanes per node (GS = 16 or 64); prefetch (u,du) per chunk, shfl-broadcast,
// 4-way unrolled gather for ILP.

template <int WD, int GS, bool BIAS, bool RELU>
__global__ __launch_bounds__(256) void aggregate_scalar_kernel(
    const float* __restrict__ H, const float* __restrict__ dinv,
    const int* __restrict__ row_ptr, const int* __restrict__ col_src,
    const float* __restrict__ bias, float* __restrict__ out) {
    const int NPB = 256 / GS;
    int v = blockIdx.x * NPB + (threadIdx.x / GS);
    int lg = threadIdx.x & (GS - 1);
    if (v >= NN) return;
    bool act = (WD == GS) ? true : (lg < WD);
    float dv = dinv[v];
    int beg = row_ptr[v], end = row_ptr[v + 1];
    float self = act ? H[(size_t)v * WD + lg] : 0.0f;
    float acc = 0.0f;
    for (int cbeg = beg; cbeg < end; cbeg += GS) {
        int cnt = min(GS, end - cbeg);
        int u_l = (lg < cnt) ? col_src[cbeg + lg] : 0;
        float w_l = (lg < cnt) ? dinv[u_l] : 0.0f;
        int e = 0;
        for (; e + 4 <= cnt; e += 4) {
            int u0 = __shfl(u_l, e + 0, GS); float w0 = __shfl(w_l, e + 0, GS);
            int u1 = __shfl(u_l, e + 1, GS); float w1 = __shfl(w_l, e + 1, GS);
            int u2 = __shfl(u_l, e + 2, GS); float w2 = __shfl(w_l, e + 2, GS);
            int u3 = __shfl(u_l, e + 3, GS); float w3 = __shfl(w_l, e + 3, GS);
            float h0 = act ? H[(size_t)u0 * WD + lg] : 0.0f;
            float h1 = act ? H[(size_t)u1 * WD + lg] : 0.0f;
            float h2 = act ? H[(size_t)u2 * WD + lg] : 0.0f;
            float h3 = act ? H[(size_t)u3 * WD + lg] : 0.0f;
            acc = fmaf(w0, h0, acc);
            acc = fmaf(w1, h1, acc);
            acc = fmaf(w2, h2, acc);
            acc = fmaf(w3, h3, acc);
        }
        for (; e < cnt; ++e) {
            int u = __shfl(u_l, e, GS);
            float w = __shfl(w_l, e, GS);
            float h = act ? H[(size_t)u * WD + lg] : 0.0f;
            acc = fmaf(w, h, acc);
        }
    }
    float r = dv * acc + dv * dv * self;
    if (act) {
        if (BIAS) r += bias[lg];
        if (RELU) r = fmaxf(r, 0.0f);
        out[(size_t)v * WD + lg] = r;
    }
}

// width 256: one wave per node, float4 per lane
template <bool BIAS, bool RELU>
__global__ __launch_bounds__(256) void aggregate_v4_256_kernel(
    const float* __restrict__ H, const float* __restrict__ dinv,
    const int* __restrict__ row_ptr, const int* __restrict__ col_src,
    const float* __restrict__ bias, float* __restrict__ out) {
    int v = blockIdx.x * 4 + (threadIdx.x >> 6);
    int lane = threadIdx.x & 63;
    if (v >= NN) return;
    const float4* Hv = (const float4*)H;
    float dv = dinv[v];
    int beg = row_ptr[v], end = row_ptr[v + 1];
    float4 self = Hv[(size_t)v * 64 + lane];
    float4 acc = make_float4(0.f, 0.f, 0.f, 0.f);
    for (int cbeg = beg; cbeg < end; cbeg += 64) {
        int cnt = min(64, end - cbeg);
        int u_l = (lane < cnt) ? col_src[cbeg + lane] : 0;
        float w_l = (lane < cnt) ? dinv[u_l] : 0.0f;
        int e = 0;
        for (; e + 4 <= cnt; e += 4) {
            int u0 = __shfl(u_l, e + 0); float w0 = __shfl(w_l, e + 0);
            int u1 = __shfl(u_l, e + 1); float w1 = __shfl(w_l, e + 1);
            int u2 = __shfl(u_l, e + 2); float w2 = __shfl(w_l, e + 2);
            int u3 = __shfl(u_l, e + 3); float w3 = __shfl(w_l, e + 3);
            float4 h0 = Hv[(size_t)u0 * 64 + lane];
            float4 h1 = Hv[(size_t)u1 * 64 + lane];
            float4 h2 = Hv[(size_t)u2 * 64 + lane];
            float4 h3 = Hv[(size_t)u3 * 64 + lane];
            acc.x = fmaf(w0, h0.x, acc.x); acc.y = fmaf(w0, h0.y, acc.y);
            acc.z = fmaf(w0, h0.z, acc.z); acc.w = fmaf(w0, h0.w, acc.w);
            acc.x = fmaf(w1, h1.x, acc.x); acc.y = fmaf(w1, h1.y, acc.y);
            acc.z = fmaf(w1, h1.z, acc.z); acc.w = fmaf(w1, h1.w, acc.w);
            acc.x = fmaf(w2, h2.x, acc.x); acc.y = fmaf(w2, h2.y, acc.y);
            acc.z = fmaf(w2, h2.z, acc.z); acc.w = fmaf(w2, h2.w, acc.w);
            acc.x = fmaf(w3, h3.x, acc.x); acc.y = fmaf(w3, h3.y, acc.y);
            acc.z = fmaf(w3, h3.z, acc.z); acc.w = fmaf(w3, h3.w, acc.w);
        }
        for (; e < cnt; ++e) {
            int u = __shfl(u_l, e);
            float w = __shfl(w_l, e);
            float4 h = Hv[(size_t)u * 64 + lane];
            acc.x = fmaf(w, h.x, acc.x); acc.y = fmaf(w, h.y, acc.y);
            acc.z = fmaf(w, h.z, acc.z); acc.w = fmaf(w, h.w, acc.w);
        }
    }
    float dv2 = dv * dv;
    float4 r;
    r.x = fmaf(dv, acc.x, dv2 * self.x);
    r.y = fmaf(dv, acc.y, dv2 * self.y);
    r.z = fmaf(dv, acc.z, dv2 * self.z);
    r.w = fmaf(dv, acc.w, dv2 * self.w);
    if (BIAS) {
        float4 b = ((const float4*)bias)[lane];
        r.x += b.x; r.y += b.y; r.z += b.z; r.w += b.w;
    }
    if (RELU) {
        r.x = fmaxf(r.x, 0.f); r.y = fmaxf(r.y, 0.f);
        r.z = fmaxf(r.z, 0.f); r.w = fmaxf(r.w, 0.f);
    }
    ((float4*)out)[(size_t)v * 64 + lane] = r;
}

// ---------------- fp32 GEMM, 128x128x8 tile, 8x8/thread ----------------
// Requires Nd % 128 == 0, K % 8 == 0. Rows padded to 132 floats (16B-aligned)
// so every inner-loop LDS access is ds_read_b128 with <=2-way bank aliasing.

template <bool BIASRELU>
__global__ __launch_bounds__(256, 2) void gemm_big_kernel(
    const float* __restrict__ A, const float* __restrict__ W,
    const float* __restrict__ bias, float* __restrict__ C,
    int M, int K, int Nd) {
    const int BK = 8;
    __shared__ float As[BK][132];
    __shared__ float Ws[BK][132];
    int bm = blockIdx.y * 128;
    int bn = blockIdx.x * 128;
    int tid = threadIdx.x;
    int tx = tid & 15;
    int ty = tid >> 4;

    // staging maps
    int ar = tid >> 1;            // 0..127 A row
    int ac = (tid & 1) * 4;       // k offset {0,4}
    int wn = (tid & 31) * 4;      // 0..124 W col
    int wk = tid >> 5;            // 0..7 W k-row

    float acc[8][8];
#pragma unroll
    for (int i = 0; i < 8; ++i)
#pragma unroll
        for (int j = 0; j < 8; ++j) acc[i][j] = 0.0f;

    for (int k0 = 0; k0 < K; k0 += BK) {
        int gm = bm + ar;
        float4 av = make_float4(0.f, 0.f, 0.f, 0.f);
        if (gm < M) av = *(const float4*)&A[(size_t)gm * K + k0 + ac];
        float4 wv = *(const float4*)&W[(size_t)(k0 + wk) * Nd + bn + wn];
        __syncthreads();
        As[ac + 0][ar] = av.x;
        As[ac + 1][ar] = av.y;
        As[ac + 2][ar] = av.z;
        As[ac + 3][ar] = av.w;
        *(float4*)&Ws[wk][wn] = wv;
        __syncthreads();
#pragma unroll
        for (int kk = 0; kk < BK; ++kk) {
            float4 a0 = *(const float4*)&As[kk][ty * 4];
            float4 a1 = *(const float4*)&As[kk][64 + ty * 4];
            float4 b0 = *(const float4*)&Ws[kk][tx * 4];
            float4 b1 = *(const float4*)&Ws[kk][64 + tx * 4];
            float af[8] = {a0.x, a0.y, a0.z, a0.w, a1.x, a1.y, a1.z, a1.w};
            float bf[8] = {b0.x, b0.y, b0.z, b0.w, b1.x, b1.y, b1.z, b1.w};
#pragma unroll
            for (int i = 0; i < 8; ++i)
#pragma unroll
                for (int j = 0; j < 8; ++j) acc[i][j] = fmaf(af[i], bf[j], acc[i][j]);
        }
    }

    float4 bi0 = make_float4(0.f, 0.f, 0.f, 0.f), bi1 = bi0;
    if (BIASRELU) {
        bi0 = *(const float4*)&bias[bn + tx * 4];
        bi1 = *(const float4*)&bias[bn + 64 + tx * 4];
    }
#pragma unroll
    for (int i = 0; i < 8; ++i) {
        int m = bm + ((i < 4) ? (ty * 4 + i) : (64 + ty * 4 + i - 4));
        if (m >= M) continue;
        float4 r0 = make_float4(acc[i][0], acc[i][1], acc[i][2], acc[i][3]);
        float4 r1 = make_float4(acc[i][4], acc[i][5], acc[i][6], acc[i][7]);
        if (BIASRELU) {
            r0.x = fmaxf(r0.x + bi0.x, 0.f); r0.y = fmaxf(r0.y + bi0.y, 0.f);
            r0.z = fmaxf(r0.z + bi0.z, 0.f); r0.w = fmaxf(r0.w + bi0.w, 0.f);
            r1.x = fmaxf(r1.x + bi1.x, 0.f); r1.y = fmaxf(r1.y + bi1.y, 0.f);
            r1.z = fmaxf(r1.z + bi1.z, 0.f); r1.w = fmaxf(r1.w + bi1.w, 0.f);
        }
        *(float4*)&C[(size_t)m * Nd + bn + tx * 4] = r0;
        *(float4*)&C[(size_t)m * Nd + bn + 64 + tx * 4] = r1;
    }
}

// ---------------- fp32 GEMM, 64x64x16 tile, 4x4/thread (small Nd) ----------------

template <bool BIASRELU>
__global__ __launch_bounds__(256, 4) void gemm_small_kernel(
    const float* __restrict__ A, const float* __restrict__ W,
    const float* __restrict__ bias, float* __restrict__ C,
    int M, int K, int Nd) {
    const int BK = 16;
    __shared__ float As[BK][68];
    __shared__ float Ws[BK][68];
    int bm = blockIdx.y * 64;
    int bn = blockIdx.x * 64;
    int tid = threadIdx.x;
    int tx = tid & 15;
    int ty = tid >> 4;

    int ar = tid >> 2;           // 0..63
    int ac = (tid & 3) * 4;      // {0,4,8,12}
    int wcol = tid & 63;
    int wk0 = (tid >> 6) * 4;

    float acc[4][4];
#pragma unroll
    for (int i = 0; i < 4; ++i)
#pragma unroll
        for (int j = 0; j < 4; ++j) acc[i][j] = 0.0f;

    for (int k0 = 0; k0 < K; k0 += BK) {
        int gm = bm + ar;
        float a0 = 0.f, a1 = 0.f, a2 = 0.f, a3 = 0.f;
        if (gm < M) {
            const float* ap = &A[(size_t)gm * K];
            int gk = k0 + ac;
            a0 = (gk + 0 < K) ? ap[gk + 0] : 0.f;
            a1 = (gk + 1 < K) ? ap[gk + 1] : 0.f;
            a2 = (gk + 2 < K) ? ap[gk + 2] : 0.f;
            a3 = (gk + 3 < K) ? ap[gk + 3] : 0.f;
        }
        float w0 = 0.f, w1 = 0.f, w2 = 0.f, w3 = 0.f;
        if (bn + wcol < Nd) {
            int gk = k0 + wk0;
            w0 = (gk + 0 < K) ? W[(size_t)(gk + 0) * Nd + bn + wcol] : 0.f;
            w1 = (gk + 1 < K) ? W[(size_t)(gk + 1) * Nd + bn + wcol] : 0.f;
            w2 = (gk + 2 < K) ? W[(size_t)(gk + 2) * Nd + bn + wcol] : 0.f;
            w3 = (gk + 3 < K) ? W[(size_t)(gk + 3) * Nd + bn + wcol] : 0.f;
        }
        __syncthreads();
        As[ac + 0][ar] = a0;
        As[ac + 1][ar] = a1;
        As[ac + 2][ar] = a2;
        As[ac + 3][ar] = a3;
        Ws[wk0 + 0][wcol] = w0;
        Ws[wk0 + 1][wcol] = w1;
        Ws[wk0 + 2][wcol] = w2;
        Ws[wk0 + 3][wcol] = w3;
        __syncthreads();
#pragma unroll
        for (int kk = 0; kk < BK; ++kk) {
            float4 a = *(const float4*)&As[kk][ty * 4];
            float4 b = *(const float4*)&Ws[kk][tx * 4];
            float af[4] = {a.x, a.y, a.z, a.w};
            float bf[4] = {b.x, b.y, b.z, b.w};
#pragma unroll
            for (int i = 0; i < 4; ++i)
#pragma unroll
                for (int j = 0; j < 4; ++j) acc[i][j] = fmaf(af[i], bf[j], acc[i][j]);
        }
    }

    int col = bn + tx * 4;
    if (col >= Nd) return;
    float4 bi = make_float4(0.f, 0.f, 0.f, 0.f);
    if (BIASRELU) bi = *(const float4*)&bias[col];
#pragma unroll
    for (int i = 0; i < 4; ++i) {
        int m = bm + ty * 4 + i;
        if (m >= M) continue;
        float4 r = make_float4(acc[i][0], acc[i][1], acc[i][2], acc[i][3]);
        if (BIASRELU) {
            r.x = fmaxf(r.x + bi.x, 0.f); r.y = fmaxf(r.y + bi.y, 0.f);
            r.z = fmaxf(r.z + bi.z, 0.f); r.w = fmaxf(r.w + bi.w, 0.f);
        }
        *(float4*)&C[(size_t)m * Nd + col] = r;
    }
}

// ---------------- launch ----------------

extern "C" void kernel_launch(void* const* d_in, const int* in_sizes, int n_in,
                              void* d_out, int out_size, void* d_ws, size_t ws_size,
                              hipStream_t stream) {
    const float* x = (const float*)d_in[0];
    const int* ei = (const int*)d_in[1];
    const int* e_src = ei;
    const int* e_dst = ei + NE;
    const float* W1 = (const float*)d_in[2];
    const float* b1 = (const float*)d_in[3];
    const float* W2 = (const float*)d_in[4];
    const float* b2 = (const float*)d_in[5];
    const float* W3 = (const float*)d_in[6];
    const float* b3 = (const float*)d_in[7];
    const float* W4 = (const float*)d_in[8];
    const float* b4 = (const float*)d_in[9];
    const float* W5 = (const float*)d_in[10];
    const float* b5 = (const float*)d_in[11];
    const float* W6 = (const float*)d_in[12];
    const float* b6 = (const float*)d_in[13];
    float* out = (float*)d_out;

    float* bufA = (float*)d_ws;
    float* bufB = bufA + (size_t)NN * 512;
    float* dinv = bufB + (size_t)NN * 512;
    int* deg = (int*)(dinv + NN);
    int* row_ptr = deg + NN;
    int* cursor = row_ptr + NN + 1;
    int* col_src = cursor + NN;
    int* blk = col_src + NE;

    const int nblkN = (NN + 255) / 256;
    const int nblkE = (NE + 255) / 256;

    zero_int_kernel<<<nblkN, 256, 0, stream>>>(deg, NN);
    count_deg_kernel<<<nblkE, 256, 0, stream>>>(e_dst, deg);
    dinv_kernel<<<nblkN, 256, 0, stream>>>(deg, dinv);
    scan_blocks_kernel<<<nblkN, 256, 0, stream>>>(deg, row_ptr, blk, NN);
    scan_sums_kernel<<<1, 256, 0, stream>>>(blk, nblkN, row_ptr, NN);
    scan_add_kernel<<<nblkN, 256, 0, stream>>>(row_ptr, blk, cursor, NN);
    scatter_kernel<<<nblkE, 256, 0, stream>>>(e_src, e_dst, cursor, col_src);

    const int aggGrid64 = (NN + 3) / 4;    // 4 nodes/block (64-lane groups)
    const int aggGrid16 = (NN + 15) / 16;  // 16 nodes/block (16-lane groups)

    // L1: agg(x,35) -> bufA ; relu(bufA@W1+b1) -> bufB (64)
    aggregate_scalar_kernel<35, 64, false, false><<<aggGrid64, 256, 0, stream>>>(
        x, dinv, row_ptr, col_src, nullptr, bufA);
    {
        dim3 g(1, (NN + 63) / 64);
        gemm_small_kernel<true><<<g, 256, 0, stream>>>(bufA, W1, b1, bufB, NN, 35, 64);
    }
    // L2: agg(bufB,64) -> bufA ; relu(bufA@W2+b2) -> bufB (256)
    aggregate_scalar_kernel<64, 64, false, false><<<aggGrid64, 256, 0, stream>>>(
        bufB, dinv, row_ptr, col_src, nullptr, bufA);
    {
        dim3 g(256 / 128, (NN + 127) / 128);
        gemm_big_kernel<true><<<g, 256, 0, stream>>>(bufA, W2, b2, bufB, NN, 64, 256);
    }
    // L3: agg(bufB,256) -> bufA ; relu(bufA@W3+b3) -> bufB (512)
    aggregate_v4_256_kernel<false, false><<<aggGrid64, 256, 0, stream>>>(
        bufB, dinv, row_ptr, col_src, nullptr, bufA);
    {
        dim3 g(512 / 128, (NN + 127) / 128);
        gemm_big_kernel<true><<<g, 256, 0, stream>>>(bufA, W3, b3, bufB, NN, 256, 512);
    }
    // L4: bufB@W4 -> bufA (256) ; relu(S*bufA+b4) -> bufB
    {
        dim3 g(256 / 128, (NN + 127) / 128);
        gemm_big_kernel<false><<<g, 256, 0, stream>>>(bufB, W4, nullptr, bufA, NN, 512, 256);
    }
    aggregate_v4_256_kernel<true, true><<<aggGrid64, 256, 0, stream>>>(
        bufA, dinv, row_ptr, col_src, b4, bufB);
    // L5: bufB@W5 -> bufA (64) ; relu(S*bufA+b5) -> bufB
    {
        dim3 g(1, (NN + 63) / 64);
        gemm_small_kernel<false><<<g, 256, 0, stream>>>(bufB, W5, nullptr, bufA, NN, 256, 64);
    }
    aggregate_scalar_kernel<64, 64, true, true><<<aggGrid64, 256, 0, stream>>>(
        bufA, dinv, row_ptr, col_src, b5, bufB);
    // L6: bufB@W6 -> bufA (16) ; S*bufA+b6 -> out
    {
        dim3 g(1, (NN + 63) / 64);
        gemm_small_kernel<false><<<g, 256, 0, stream>>>(bufB, W6, nullptr, bufA, NN, 64, 16);
    }
    aggregate_scalar_kernel<16, 16, true, false><<<aggGrid16, 256, 0, stream>>>(
        bufA, dinv, row_ptr, col_src, b6, out);
}

// Round 4
// 774.191 us; speedup vs baseline: 1.9974x; 1.2393x over previous
//
#include <hip/hip_runtime.h>

#define NN 50000
#define NE 800000

typedef __attribute__((ext_vector_type(8))) short bf16x8;
typedef __attribute__((ext_vector_type(4))) float f32x4;

__device__ inline ushort f2bf(float f) {
    union { float f; unsigned u; } v; v.f = f;
    unsigned r = (v.u + 0x7FFFu + ((v.u >> 16) & 1u)) >> 16;  // RNE
    return (ushort)r;
}
__device__ inline float bf2f(ushort h) {
    union { float f; unsigned u; } v; v.u = ((unsigned)h) << 16;
    return v.f;
}

// ---------------- CSR build ----------------

__global__ __launch_bounds__(256) void zero_int_kernel(int* __restrict__ p, int n) {
    int i = blockIdx.x * 256 + threadIdx.x;
    if (i < n) p[i] = 0;
}

__global__ __launch_bounds__(256) void count_deg_kernel(const int* __restrict__ dst,
                                                        int* __restrict__ deg) {
    int e = blockIdx.x * 256 + threadIdx.x;
    if (e < NE) atomicAdd(&deg[dst[e]], 1);
}

__global__ __launch_bounds__(256) void dinv_kernel(const int* __restrict__ deg,
                                                   float* __restrict__ dinv) {
    int v = blockIdx.x * 256 + threadIdx.x;
    if (v < NN) dinv[v] = rsqrtf((float)(deg[v] + 1));  // +1 self loop
}

__global__ __launch_bounds__(256) void scan_blocks_kernel(const int* __restrict__ deg,
                                                          int* __restrict__ out,
                                                          int* __restrict__ blk, int n) {
    __shared__ int s[256];
    int tid = threadIdx.x;
    int i = blockIdx.x * 256 + tid;
    int v = (i < n) ? deg[i] : 0;
    s[tid] = v;
    __syncthreads();
    for (int off = 1; off < 256; off <<= 1) {
        int t = (tid >= off) ? s[tid - off] : 0;
        __syncthreads();
        s[tid] += t;
        __syncthreads();
    }
    if (i < n) out[i] = s[tid] - v;
    if (tid == 255) blk[blockIdx.x] = s[255];
}

__global__ __launch_bounds__(256) void scan_sums_kernel(int* __restrict__ blk, int nb,
                                                        int* __restrict__ row_ptr, int n) {
    __shared__ int s[256];
    int tid = threadIdx.x;
    int v = (tid < nb) ? blk[tid] : 0;
    s[tid] = v;
    __syncthreads();
    for (int off = 1; off < 256; off <<= 1) {
        int t = (tid >= off) ? s[tid - off] : 0;
        __syncthreads();
        s[tid] += t;
        __syncthreads();
    }
    if (tid < nb) blk[tid] = s[tid] - v;
    if (tid == 255) row_ptr[n] = s[255];
}

__global__ __launch_bounds__(256) void scan_add_kernel(int* __restrict__ row_ptr,
                                                       const int* __restrict__ blk,
                                                       int* __restrict__ cursor, int n) {
    int i = blockIdx.x * 256 + threadIdx.x;
    if (i < n) {
        int r = row_ptr[i] + blk[blockIdx.x];
        row_ptr[i] = r;
        cursor[i] = r;
    }
}

__global__ __launch_bounds__(256) void scatter_kernel(const int* __restrict__ src,
                                                      const int* __restrict__ dst,
                                                      int* __restrict__ cursor,
                                                      int* __restrict__ col_src) {
    int e = blockIdx.x * 256 + threadIdx.x;
    if (e < NE) {
        int d = dst[e];
        int pos = atomicAdd(&cursor[d], 1);
        col_src[pos] = src[e];
    }
}

// ---------------- weight split + transpose: W[K][Nd] fp32 -> Wt_hi/Wt_lo [Nd][K] bf16 ----

__global__ __launch_bounds__(256) void split_w_kernel(const float* __restrict__ W,
                                                      ushort* __restrict__ Wth,
                                                      ushort* __restrict__ Wtl,
                                                      int K, int Nd) {
    int i = blockIdx.x * 256 + threadIdx.x;
    if (i >= K * Nd) return;
    int k = i / Nd, n = i - k * Nd;
    float w = W[i];
    ushort h = f2bf(w);
    Wth[(size_t)n * K + k] = h;
    Wtl[(size_t)n * K + k] = f2bf(w - bf2f(h));
}

// ------- aggregation: out[v] = dv*sum du*H[u] + dv^2*H[v] (+bias,relu | hilo) -------

template <int WD, int GS, bool BIAS, bool RELU, bool HILO>
__global__ __launch_bounds__(256) void aggregate_scalar_kernel(
    const float* __restrict__ H, const float* __restrict__ dinv,
    const int* __restrict__ row_ptr, const int* __restrict__ col_src,
    const float* __restrict__ bias, float* __restrict__ out,
    ushort* __restrict__ oh, ushort* __restrict__ ol) {
    const int NPB = 256 / GS;
    int v = blockIdx.x * NPB + (threadIdx.x / GS);
    int lg = threadIdx.x & (GS - 1);
    if (v >= NN) return;
    bool act = (WD == GS) ? true : (lg < WD);
    float dv = dinv[v];
    int beg = row_ptr[v], end = row_ptr[v + 1];
    float self = act ? H[(size_t)v * WD + lg] : 0.0f;
    float acc = 0.0f;
    for (int cbeg = beg; cbeg < end; cbeg += GS) {
        int cnt = min(GS, end - cbeg);
        int u_l = (lg < cnt) ? col_src[cbeg + lg] : 0;
        float w_l = (lg < cnt) ? dinv[u_l] : 0.0f;
        int e = 0;
        for (; e + 4 <= cnt; e += 4) {
            int u0 = __shfl(u_l, e + 0, GS); float w0 = __shfl(w_l, e + 0, GS);
            int u1 = __shfl(u_l, e + 1, GS); float w1 = __shfl(w_l, e + 1, GS);
            int u2 = __shfl(u_l, e + 2, GS); float w2 = __shfl(w_l, e + 2, GS);
            int u3 = __shfl(u_l, e + 3, GS); float w3 = __shfl(w_l, e + 3, GS);
            float h0 = act ? H[(size_t)u0 * WD + lg] : 0.0f;
            float h1 = act ? H[(size_t)u1 * WD + lg] : 0.0f;
            float h2 = act ? H[(size_t)u2 * WD + lg] : 0.0f;
            float h3 = act ? H[(size_t)u3 * WD + lg] : 0.0f;
            acc = fmaf(w0, h0, acc);
            acc = fmaf(w1, h1, acc);
            acc = fmaf(w2, h2, acc);
            acc = fmaf(w3, h3, acc);
        }
        for (; e < cnt; ++e) {
            int u = __shfl(u_l, e, GS);
            float w = __shfl(w_l, e, GS);
            float h = act ? H[(size_t)u * WD + lg] : 0.0f;
            acc = fmaf(w, h, acc);
        }
    }
    float r = dv * acc + dv * dv * self;
    if (act) {
        if (BIAS) r += bias[lg];
        if (RELU) r = fmaxf(r, 0.0f);
        if (HILO) {
            ushort h = f2bf(r);
            oh[(size_t)v * WD + lg] = h;
            ol[(size_t)v * WD + lg] = f2bf(r - bf2f(h));
        } else {
            out[(size_t)v * WD + lg] = r;
        }
    }
}

// width 256: one wave per node, float4 per lane
template <bool BIAS, bool RELU, bool HILO>
__global__ __launch_bounds__(256) void aggregate_v4_256_kernel(
    const float* __restrict__ H, const float* __restrict__ dinv,
    const int* __restrict__ row_ptr, const int* __restrict__ col_src,
    const float* __restrict__ bias, float* __restrict__ out,
    ushort* __restrict__ oh, ushort* __restrict__ ol) {
    int v = blockIdx.x * 4 + (threadIdx.x >> 6);
    int lane = threadIdx.x & 63;
    if (v >= NN) return;
    const float4* Hv = (const float4*)H;
    float dv = dinv[v];
    int beg = row_ptr[v], end = row_ptr[v + 1];
    float4 self = Hv[(size_t)v * 64 + lane];
    float4 acc = make_float4(0.f, 0.f, 0.f, 0.f);
    for (int cbeg = beg; cbeg < end; cbeg += 64) {
        int cnt = min(64, end - cbeg);
        int u_l = (lane < cnt) ? col_src[cbeg + lane] : 0;
        float w_l = (lane < cnt) ? dinv[u_l] : 0.0f;
        int e = 0;
        for (; e + 4 <= cnt; e += 4) {
            int u0 = __shfl(u_l, e + 0); float w0 = __shfl(w_l, e + 0);
            int u1 = __shfl(u_l, e + 1); float w1 = __shfl(w_l, e + 1);
            int u2 = __shfl(u_l, e + 2); float w2 = __shfl(w_l, e + 2);
            int u3 = __shfl(u_l, e + 3); float w3 = __shfl(w_l, e + 3);
            float4 h0 = Hv[(size_t)u0 * 64 + lane];
            float4 h1 = Hv[(size_t)u1 * 64 + lane];
            float4 h2 = Hv[(size_t)u2 * 64 + lane];
            float4 h3 = Hv[(size_t)u3 * 64 + lane];
            acc.x = fmaf(w0, h0.x, acc.x); acc.y = fmaf(w0, h0.y, acc.y);
            acc.z = fmaf(w0, h0.z, acc.z); acc.w = fmaf(w0, h0.w, acc.w);
            acc.x = fmaf(w1, h1.x, acc.x); acc.y = fmaf(w1, h1.y, acc.y);
            acc.z = fmaf(w1, h1.z, acc.z); acc.w = fmaf(w1, h1.w, acc.w);
            acc.x = fmaf(w2, h2.x, acc.x); acc.y = fmaf(w2, h2.y, acc.y);
            acc.z = fmaf(w2, h2.z, acc.z); acc.w = fmaf(w2, h2.w, acc.w);
            acc.x = fmaf(w3, h3.x, acc.x); acc.y = fmaf(w3, h3.y, acc.y);
            acc.z = fmaf(w3, h3.z, acc.z); acc.w = fmaf(w3, h3.w, acc.w);
        }
        for (; e < cnt; ++e) {
            int u = __shfl(u_l, e);
            float w = __shfl(w_l, e);
            float4 h = Hv[(size_t)u * 64 + lane];
            acc.x = fmaf(w, h.x, acc.x); acc.y = fmaf(w, h.y, acc.y);
            acc.z = fmaf(w, h.z, acc.z); acc.w = fmaf(w, h.w, acc.w);
        }
    }
    float dv2 = dv * dv;
    float4 r;
    r.x = fmaf(dv, acc.x, dv2 * self.x);
    r.y = fmaf(dv, acc.y, dv2 * self.y);
    r.z = fmaf(dv, acc.z, dv2 * self.z);
    r.w = fmaf(dv, acc.w, dv2 * self.w);
    if (BIAS) {
        float4 b = ((const float4*)bias)[lane];
        r.x += b.x; r.y += b.y; r.z += b.z; r.w += b.w;
    }
    if (RELU) {
        r.x = fmaxf(r.x, 0.f); r.y = fmaxf(r.y, 0.f);
        r.z = fmaxf(r.z, 0.f); r.w = fmaxf(r.w, 0.f);
    }
    if (HILO) {
        ushort4 hv, lv;
        hv.x = f2bf(r.x); lv.x = f2bf(r.x - bf2f(hv.x));
        hv.y = f2bf(r.y); lv.y = f2bf(r.y - bf2f(hv.y));
        hv.z = f2bf(r.z); lv.z = f2bf(r.z - bf2f(hv.z));
        hv.w = f2bf(r.w); lv.w = f2bf(r.w - bf2f(hv.w));
        *(ushort4*)&oh[(size_t)v * 256 + lane * 4] = hv;
        *(ushort4*)&ol[(size_t)v * 256 + lane * 4] = lv;
    } else {
        ((float4*)out)[(size_t)v * 64 + lane] = r;
    }
}

// ---------------- split-bf16 MFMA GEMM: C = A @ Wt^T  (A: M x K, Wt: Nd x K) ----------
// 128x128 tile, 4 waves in 2x2, each wave 4x4 of 16x16x32 MFMA tiles.
// fp32 emulated via 3 MFMAs: hi*hi + lo*hi + hi*lo (error ~2^-16 relative).
// LDS rows padded to 40 shorts (80 B): 16B-aligned ds_read_b128, conflict-free.
// EPI: 0 = fp32 out; 1 = fp32 bias+relu; 2 = bf16 hi/lo out, bias+relu.

template <int EPI>
__global__ __launch_bounds__(256, 2) void gemm_bf16x3_kernel(
    const ushort* __restrict__ Ah, const ushort* __restrict__ Al,
    const ushort* __restrict__ Bh, const ushort* __restrict__ Bl,
    const float* __restrict__ bias, float* __restrict__ Cf,
    ushort* __restrict__ Ch, ushort* __restrict__ Cl,
    int M, int K, int Nd) {
    __shared__ short At[2][128][40];
    __shared__ short Bt[2][128][40];
    int tid = threadIdx.x;
    int bm = blockIdx.y * 128, bn = blockIdx.x * 128;
    int lane = tid & 63;
    int wave = tid >> 6;
    int q = lane >> 4, l15 = lane & 15;
    int wm = (wave & 1) * 64, wn = (wave >> 1) * 64;
    int sr = tid >> 1, sc = (tid & 1) * 16;  // staging: row, 16-short half

    f32x4 zero4 = {0.f, 0.f, 0.f, 0.f};
    f32x4 acc[4][4];
#pragma unroll
    for (int i = 0; i < 4; ++i)
#pragma unroll
        for (int j = 0; j < 4; ++j) acc[i][j] = zero4;

    bool arow_ok = (bm + sr) < M;
    const ushort* Aph = Ah + (size_t)(bm + sr) * K + sc;
    const ushort* Apl = Al + (size_t)(bm + sr) * K + sc;
    const ushort* Bph = Bh + (size_t)(bn + sr) * K + sc;
    const ushort* Bpl = Bl + (size_t)(bn + sr) * K + sc;

    for (int k0 = 0; k0 < K; k0 += 32) {
        int4 z = {0, 0, 0, 0};
        int4 vah0 = z, vah1 = z, val0 = z, val1 = z;
        if (arow_ok) {
            vah0 = *(const int4*)(Aph + k0);
            vah1 = *(const int4*)(Aph + k0 + 8);
            val0 = *(const int4*)(Apl + k0);
            val1 = *(const int4*)(Apl + k0 + 8);
        }
        int4 vbh0 = *(const int4*)(Bph + k0);
        int4 vbh1 = *(const int4*)(Bph + k0 + 8);
        int4 vbl0 = *(const int4*)(Bpl + k0);
        int4 vbl1 = *(const int4*)(Bpl + k0 + 8);
        __syncthreads();
        *(int4*)&At[0][sr][sc] = vah0;
        *(int4*)&At[0][sr][sc + 8] = vah1;
        *(int4*)&At[1][sr][sc] = val0;
        *(int4*)&At[1][sr][sc + 8] = val1;
        *(int4*)&Bt[0][sr][sc] = vbh0;
        *(int4*)&Bt[0][sr][sc + 8] = vbh1;
        *(int4*)&Bt[1][sr][sc] = vbl0;
        *(int4*)&Bt[1][sr][sc + 8] = vbl1;
        __syncthreads();

        bf16x8 ah[4], al[4];
#pragma unroll
        for (int i = 0; i < 4; ++i) {
            ah[i] = *(const bf16x8*)&At[0][wm + i * 16 + l15][q * 8];
            al[i] = *(const bf16x8*)&At[1][wm + i * 16 + l15][q * 8];
        }
#pragma unroll
        for (int j = 0; j < 4; ++j) {
            bf16x8 bh = *(const bf16x8*)&Bt[0][wn + j * 16 + l15][q * 8];
            bf16x8 bl = *(const bf16x8*)&Bt[1][wn + j * 16 + l15][q * 8];
#pragma unroll
            for (int i = 0; i < 4; ++i) {
                acc[i][j] = __builtin_amdgcn_mfma_f32_16x16x32_bf16(ah[i], bh, acc[i][j], 0, 0, 0);
                acc[i][j] = __builtin_amdgcn_mfma_f32_16x16x32_bf16(al[i], bh, acc[i][j], 0, 0, 0);
                acc[i][j] = __builtin_amdgcn_mfma_f32_16x16x32_bf16(ah[i], bl, acc[i][j], 0, 0, 0);
            }
        }
    }

    // epilogue: C row m = bm+wm+i*16+q*4+r, col n = bn+wn+j*16+l15
#pragma unroll
    for (int j = 0; j < 4; ++j) {
        int n = bn + wn + j * 16 + l15;
        float bv = (EPI >= 1) ? bias[n] : 0.0f;
#pragma unroll
        for (int i = 0; i < 4; ++i) {
            int mb = bm + wm + i * 16 + q * 4;
#pragma unroll
            for (int r = 0; r < 4; ++r) {
                int m = mb + r;
                if (m >= M) continue;
                float v = acc[i][j][r];
                if (EPI >= 1) v = fmaxf(v + bv, 0.0f);
                if (EPI == 2) {
                    ushort h = f2bf(v);
                    Ch[(size_t)m * Nd + n] = h;
                    Cl[(size_t)m * Nd + n] = f2bf(v - bf2f(h));
                } else {
                    Cf[(size_t)m * Nd + n] = v;
                }
            }
        }
    }
}

// ---------------- fp32 GEMM, 64x64x16 tile, 4x4/thread (small layers) ----------------

template <bool BIASRELU>
__global__ __launch_bounds__(256, 4) void gemm_small_kernel(
    const float* __restrict__ A, const float* __restrict__ W,
    const float* __restrict__ bias, float* __restrict__ C,
    int M, int K, int Nd) {
    const int BK = 16;
    __shared__ float As[BK][68];
    __shared__ float Ws[BK][68];
    int bm = blockIdx.y * 64;
    int bn = blockIdx.x * 64;
    int tid = threadIdx.x;
    int tx = tid & 15;
    int ty = tid >> 4;

    int ar = tid >> 2;
    int ac = (tid & 3) * 4;
    int wcol = tid & 63;
    int wk0 = (tid >> 6) * 4;

    float acc[4][4];
#pragma unroll
    for (int i = 0; i < 4; ++i)
#pragma unroll
        for (int j = 0; j < 4; ++j) acc[i][j] = 0.0f;

    for (int k0 = 0; k0 < K; k0 += BK) {
        int gm = bm + ar;
        float a0 = 0.f, a1 = 0.f, a2 = 0.f, a3 = 0.f;
        if (gm < M) {
            const float* ap = &A[(size_t)gm * K];
            int gk = k0 + ac;
            a0 = (gk + 0 < K) ? ap[gk + 0] : 0.f;
            a1 = (gk + 1 < K) ? ap[gk + 1] : 0.f;
            a2 = (gk + 2 < K) ? ap[gk + 2] : 0.f;
            a3 = (gk + 3 < K) ? ap[gk + 3] : 0.f;
        }
        float w0 = 0.f, w1 = 0.f, w2 = 0.f, w3 = 0.f;
        if (bn + wcol < Nd) {
            int gk = k0 + wk0;
            w0 = (gk + 0 < K) ? W[(size_t)(gk + 0) * Nd + bn + wcol] : 0.f;
            w1 = (gk + 1 < K) ? W[(size_t)(gk + 1) * Nd + bn + wcol] : 0.f;
            w2 = (gk + 2 < K) ? W[(size_t)(gk + 2) * Nd + bn + wcol] : 0.f;
            w3 = (gk + 3 < K) ? W[(size_t)(gk + 3) * Nd + bn + wcol] : 0.f;
        }
        __syncthreads();
        As[ac + 0][ar] = a0;
        As[ac + 1][ar] = a1;
        As[ac + 2][ar] = a2;
        As[ac + 3][ar] = a3;
        Ws[wk0 + 0][wcol] = w0;
        Ws[wk0 + 1][wcol] = w1;
        Ws[wk0 + 2][wcol] = w2;
        Ws[wk0 + 3][wcol] = w3;
        __syncthreads();
#pragma unroll
        for (int kk = 0; kk < BK; ++kk) {
            float4 a = *(const float4*)&As[kk][ty * 4];
            float4 b = *(const float4*)&Ws[kk][tx * 4];
            float af[4] = {a.x, a.y, a.z, a.w};
            float bf[4] = {b.x, b.y, b.z, b.w};
#pragma unroll
            for (int i = 0; i < 4; ++i)
#pragma unroll
                for (int j = 0; j < 4; ++j) acc[i][j] = fmaf(af[i], bf[j], acc[i][j]);
        }
    }

    int col = bn + tx * 4;
    if (col >= Nd) return;
    float4 bi = make_float4(0.f, 0.f, 0.f, 0.f);
    if (BIASRELU) bi = *(const float4*)&bias[col];
#pragma unroll
    for (int i = 0; i < 4; ++i) {
        int m = bm + ty * 4 + i;
        if (m >= M) continue;
        float4 r = make_float4(acc[i][0], acc[i][1], acc[i][2], acc[i][3]);
        if (BIASRELU) {
            r.x = fmaxf(r.x + bi.x, 0.f); r.y = fmaxf(r.y + bi.y, 0.f);
            r.z = fmaxf(r.z + bi.z, 0.f); r.w = fmaxf(r.w + bi.w, 0.f);
        }
        *(float4*)&C[(size_t)m * Nd + col] = r;
    }
}

// ---------------- launch ----------------

extern "C" void kernel_launch(void* const* d_in, const int* in_sizes, int n_in,
                              void* d_out, int out_size, void* d_ws, size_t ws_size,
                              hipStream_t stream) {
    const float* x = (const float*)d_in[0];
    const int* ei = (const int*)d_in[1];
    const int* e_src = ei;
    const int* e_dst = ei + NE;
    const float* W1 = (const float*)d_in[2];
    const float* b1 = (const float*)d_in[3];
    const float* W2 = (const float*)d_in[4];
    const float* b2 = (const float*)d_in[5];
    const float* W3 = (const float*)d_in[6];
    const float* b3 = (const float*)d_in[7];
    const float* W4 = (const float*)d_in[8];
    const float* b4 = (const float*)d_in[9];
    const float* W5 = (const float*)d_in[10];
    const float* b5 = (const float*)d_in[11];
    const float* W6 = (const float*)d_in[12];
    const float* b6 = (const float*)d_in[13];
    float* out = (float*)d_out;

    // ---- workspace layout: 256B-aligned regions, liveness-checked ping-pong ----
    char* p = (char*)d_ws;
    auto take = [&p](size_t nbytes) {
        char* q = p;
        p += (nbytes + 255) & ~(size_t)255;
        return q;
    };
    char* RA = take((size_t)NN * 1024);   // 1 KB/node
    char* RB = take((size_t)NN * 1024);   // 1 KB/node
    char* RC = take((size_t)NN * 2048);   // 2 KB/node (X3 hi+lo @512)
    float* dinv = (float*)take((size_t)NN * 4);
    int* deg = (int*)take((size_t)NN * 4);
    int* row_ptr = (int*)take((size_t)(NN + 1) * 4);
    int* cursor = (int*)take((size_t)NN * 4);
    int* col_src = (int*)take((size_t)NE * 4);
    int* blk = (int*)take(256 * 4);
    ushort* W2th = (ushort*)take((size_t)64 * 256 * 2);
    ushort* W2tl = (ushort*)take((size_t)64 * 256 * 2);
    ushort* W3th = (ushort*)take((size_t)256 * 512 * 2);
    ushort* W3tl = (ushort*)take((size_t)256 * 512 * 2);
    ushort* W4th = (ushort*)take((size_t)512 * 256 * 2);
    ushort* W4tl = (ushort*)take((size_t)512 * 256 * 2);

    // Buffer timeline (each line: reads left, writes right; no overlap within a dispatch):
    //   agg1: x            -> A1f (RA)
    //   L1 :  A1f (RA)     -> X1f (RB)
    //   agg2: X1f (RB)     -> A2  (RC)
    //   L2 :  A2  (RC)     -> X2f (RA)
    //   agg3: X2f (RA)     -> A3  (RB)
    //   L3 :  A3  (RB)     -> X3  (RC)
    //   L4 :  X3  (RC)     -> H4f (RA)
    //   agg4: H4f (RA)     -> X4f (RB)
    //   L5 :  X4f (RB)     -> H5f (RA)
    //   agg5: H5f (RA)     -> X5f (RB)
    //   L6 :  X5f (RB)     -> H6f (RA)
    //   agg6: H6f (RA)     -> out
    float* A1f = (float*)RA;                       // NN x 35
    float* X1f = (float*)RB;                       // NN x 64
    ushort* A2h = (ushort*)RC;                     // NN x 64
    ushort* A2l = A2h + (size_t)NN * 64;
    float* X2f = (float*)RA;                       // NN x 256
    ushort* A3h = (ushort*)RB;                     // NN x 256
    ushort* A3l = A3h + (size_t)NN * 256;
    ushort* X3h = (ushort*)RC;                     // NN x 512
    ushort* X3l = X3h + (size_t)NN * 512;
    float* H4f = (float*)RA;                       // NN x 256
    float* X4f = (float*)RB;                       // NN x 256
    float* H5f = (float*)RA;                       // NN x 64
    float* X5f = (float*)RB;                       // NN x 64
    float* H6f = (float*)RA;                       // NN x 16

    const int nblkN = (NN + 255) / 256;
    const int nblkE = (NE + 255) / 256;

    // CSR build
    zero_int_kernel<<<nblkN, 256, 0, stream>>>(deg, NN);
    count_deg_kernel<<<nblkE, 256, 0, stream>>>(e_dst, deg);
    dinv_kernel<<<nblkN, 256, 0, stream>>>(deg, dinv);
    scan_blocks_kernel<<<nblkN, 256, 0, stream>>>(deg, row_ptr, blk, NN);
    scan_sums_kernel<<<1, 256, 0, stream>>>(blk, nblkN, row_ptr, NN);
    scan_add_kernel<<<nblkN, 256, 0, stream>>>(row_ptr, blk, cursor, NN);
    scatter_kernel<<<nblkE, 256, 0, stream>>>(e_src, e_dst, cursor, col_src);

    // weight splits (W2: 64x256, W3: 256x512, W4: 512x256)
    split_w_kernel<<<(64 * 256 + 255) / 256, 256, 0, stream>>>(W2, W2th, W2tl, 64, 256);
    split_w_kernel<<<(256 * 512 + 255) / 256, 256, 0, stream>>>(W3, W3th, W3tl, 256, 512);
    split_w_kernel<<<(512 * 256 + 255) / 256, 256, 0, stream>>>(W4, W4th, W4tl, 512, 256);

    const int aggGrid64 = (NN + 3) / 4;
    const int aggGrid16 = (NN + 15) / 16;
    const int mrows = (NN + 127) / 128;  // 391

    // L1: agg(x,35) -> A1f ; X1 = relu(A1f@W1+b1) -> X1f (64)
    aggregate_scalar_kernel<35, 64, false, false, false><<<aggGrid64, 256, 0, stream>>>(
        x, dinv, row_ptr, col_src, nullptr, A1f, nullptr, nullptr);
    {
        dim3 g(1, (NN + 63) / 64);
        gemm_small_kernel<true><<<g, 256, 0, stream>>>(A1f, W1, b1, X1f, NN, 35, 64);
    }
    // L2: agg(X1,64) -> A2 hi/lo ; X2 = relu(A2@W2+b2) -> X2f (256 f32)
    aggregate_scalar_kernel<64, 64, false, false, true><<<aggGrid64, 256, 0, stream>>>(
        X1f, dinv, row_ptr, col_src, nullptr, nullptr, A2h, A2l);
    {
        dim3 g(2, mrows);
        gemm_bf16x3_kernel<1><<<g, 256, 0, stream>>>(A2h, A2l, W2th, W2tl, b2,
                                                     X2f, nullptr, nullptr, NN, 64, 256);
    }
    // L3: agg(X2,256) -> A3 hi/lo ; X3 = relu(A3@W3+b3) -> X3 hi/lo (512 bf16)
    aggregate_v4_256_kernel<false, false, true><<<aggGrid64, 256, 0, stream>>>(
        X2f, dinv, row_ptr, col_src, nullptr, nullptr, A3h, A3l);
    {
        dim3 g(4, mrows);
        gemm_bf16x3_kernel<2><<<g, 256, 0, stream>>>(A3h, A3l, W3th, W3tl, b3,
                                                     nullptr, X3h, X3l, NN, 256, 512);
    }
    // L4: H4 = X3@W4 -> H4f (256 f32) ; X4 = relu(S*H4+b4) -> X4f (256 f32)
    {
        dim3 g(2, mrows);
        gemm_bf16x3_kernel<0><<<g, 256, 0, stream>>>(X3h, X3l, W4th, W4tl, nullptr,
                                                     H4f, nullptr, nullptr, NN, 512, 256);
    }
    aggregate_v4_256_kernel<true, true, false><<<aggGrid64, 256, 0, stream>>>(
        H4f, dinv, row_ptr, col_src, b4, X4f, nullptr, nullptr);
    // L5: H5 = X4@W5 -> H5f (64 f32) ; X5 = relu(S*H5+b5) -> X5f (64 f32)
    {
        dim3 g(1, (NN + 63) / 64);
        gemm_small_kernel<false><<<g, 256, 0, stream>>>(X4f, W5, nullptr, H5f, NN, 256, 64);
    }
    aggregate_scalar_kernel<64, 64, true, true, false><<<aggGrid64, 256, 0, stream>>>(
        H5f, dinv, row_ptr, col_src, b5, X5f, nullptr, nullptr);
    // L6: H6 = X5@W6 -> H6f (16 f32) ; out = S*H6 + b6
    {
        dim3 g(1, (NN + 63) / 64);
        gemm_small_kernel<false><<<g, 256, 0, stream>>>(X5f, W6, nullptr, H6f, NN, 64, 16);
    }
    aggregate_scalar_kernel<16, 16, true, false, false><<<aggGrid16, 256, 0, stream>>>(
        H6f, dinv, row_ptr, col_src, b6, out, nullptr, nullptr);
}

// Round 5
// 747.879 us; speedup vs baseline: 2.0677x; 1.0352x over previous
//
#include <hip/hip_runtime.h>

#define NN 50000
#define NE 800000

typedef __attribute__((ext_vector_type(8))) short bf16x8;
typedef __attribute__((ext_vector_type(16))) float f32x16;

__device__ inline ushort f2bf(float f) {
    union { float f; unsigned u; } v; v.f = f;
    unsigned r = (v.u + 0x7FFFu + ((v.u >> 16) & 1u)) >> 16;  // RNE
    return (ushort)r;
}
__device__ inline float bf2f(ushort h) {
    union { float f; unsigned u; } v; v.u = ((unsigned)h) << 16;
    return v.f;
}

// ---------------- CSR build ----------------

__global__ __launch_bounds__(256) void zero_int_kernel(int* __restrict__ p, int n) {
    int i = blockIdx.x * 256 + threadIdx.x;
    if (i < n) p[i] = 0;
}

__global__ __launch_bounds__(256) void count_deg_kernel(const int* __restrict__ dst,
                                                        int* __restrict__ deg) {
    int e = blockIdx.x * 256 + threadIdx.x;
    if (e < NE) atomicAdd(&deg[dst[e]], 1);
}

__global__ __launch_bounds__(256) void dinv_kernel(const int* __restrict__ deg,
                                                   float* __restrict__ dinv) {
    int v = blockIdx.x * 256 + threadIdx.x;
    if (v < NN) dinv[v] = rsqrtf((float)(deg[v] + 1));  // +1 self loop
}

__global__ __launch_bounds__(256) void scan_blocks_kernel(const int* __restrict__ deg,
                                                          int* __restrict__ out,
                                                          int* __restrict__ blk, int n) {
    __shared__ int s[256];
    int tid = threadIdx.x;
    int i = blockIdx.x * 256 + tid;
    int v = (i < n) ? deg[i] : 0;
    s[tid] = v;
    __syncthreads();
    for (int off = 1; off < 256; off <<= 1) {
        int t = (tid >= off) ? s[tid - off] : 0;
        __syncthreads();
        s[tid] += t;
        __syncthreads();
    }
    if (i < n) out[i] = s[tid] - v;
    if (tid == 255) blk[blockIdx.x] = s[255];
}

__global__ __launch_bounds__(256) void scan_sums_kernel(int* __restrict__ blk, int nb,
                                                        int* __restrict__ row_ptr, int n) {
    __shared__ int s[256];
    int tid = threadIdx.x;
    int v = (tid < nb) ? blk[tid] : 0;
    s[tid] = v;
    __syncthreads();
    for (int off = 1; off < 256; off <<= 1) {
        int t = (tid >= off) ? s[tid - off] : 0;
        __syncthreads();
        s[tid] += t;
        __syncthreads();
    }
    if (tid < nb) blk[tid] = s[tid] - v;
    if (tid == 255) row_ptr[n] = s[255];
}

__global__ __launch_bounds__(256) void scan_add_kernel(int* __restrict__ row_ptr,
                                                       const int* __restrict__ blk,
                                                       int* __restrict__ cursor, int n) {
    int i = blockIdx.x * 256 + threadIdx.x;
    if (i < n) {
        int r = row_ptr[i] + blk[blockIdx.x];
        row_ptr[i] = r;
        cursor[i] = r;
    }
}

__global__ __launch_bounds__(256) void scatter_kernel(const int* __restrict__ src,
                                                      const int* __restrict__ dst,
                                                      int* __restrict__ cursor,
                                                      int* __restrict__ col_src) {
    int e = blockIdx.x * 256 + threadIdx.x;
    if (e < NE) {
        int d = dst[e];
        int pos = atomicAdd(&cursor[d], 1);
        col_src[pos] = src[e];
    }
}

// ---------------- weight split + transpose: W[K][Nd] fp32 -> Wt_hi/Wt_lo [Nd][K] bf16 ----

__global__ __launch_bounds__(256) void split_w_kernel(const float* __restrict__ W,
                                                      ushort* __restrict__ Wth,
                                                      ushort* __restrict__ Wtl,
                                                      int K, int Nd) {
    int i = blockIdx.x * 256 + threadIdx.x;
    if (i >= K * Nd) return;
    int k = i / Nd, n = i - k * Nd;
    float w = W[i];
    ushort h = f2bf(w);
    Wth[(size_t)n * K + k] = h;
    Wtl[(size_t)n * K + k] = f2bf(w - bf2f(h));
}

// ------- aggregation: out[v] = dv*sum du*H[u] + dv^2*H[v] (+bias,relu | hilo) -------

template <int WD, int GS, bool BIAS, bool RELU, bool HILO>
__global__ __launch_bounds__(256) void aggregate_scalar_kernel(
    const float* __restrict__ H, const float* __restrict__ dinv,
    const int* __restrict__ row_ptr, const int* __restrict__ col_src,
    const float* __restrict__ bias, float* __restrict__ out,
    ushort* __restrict__ oh, ushort* __restrict__ ol) {
    const int NPB = 256 / GS;
    int v = blockIdx.x * NPB + (threadIdx.x / GS);
    int lg = threadIdx.x & (GS - 1);
    if (v >= NN) return;
    bool act = (WD == GS) ? true : (lg < WD);
    float dv = dinv[v];
    int beg = row_ptr[v], end = row_ptr[v + 1];
    float self = act ? H[(size_t)v * WD + lg] : 0.0f;
    float acc = 0.0f;
    for (int cbeg = beg; cbeg < end; cbeg += GS) {
        int cnt = min(GS, end - cbeg);
        int u_l = (lg < cnt) ? col_src[cbeg + lg] : 0;
        float w_l = (lg < cnt) ? dinv[u_l] : 0.0f;
        int e = 0;
        for (; e + 4 <= cnt; e += 4) {
            int u0 = __shfl(u_l, e + 0, GS); float w0 = __shfl(w_l, e + 0, GS);
            int u1 = __shfl(u_l, e + 1, GS); float w1 = __shfl(w_l, e + 1, GS);
            int u2 = __shfl(u_l, e + 2, GS); float w2 = __shfl(w_l, e + 2, GS);
            int u3 = __shfl(u_l, e + 3, GS); float w3 = __shfl(w_l, e + 3, GS);
            float h0 = act ? H[(size_t)u0 * WD + lg] : 0.0f;
            float h1 = act ? H[(size_t)u1 * WD + lg] : 0.0f;
            float h2 = act ? H[(size_t)u2 * WD + lg] : 0.0f;
            float h3 = act ? H[(size_t)u3 * WD + lg] : 0.0f;
            acc = fmaf(w0, h0, acc);
            acc = fmaf(w1, h1, acc);
            acc = fmaf(w2, h2, acc);
            acc = fmaf(w3, h3, acc);
        }
        for (; e < cnt; ++e) {
            int u = __shfl(u_l, e, GS);
            float w = __shfl(w_l, e, GS);
            float h = act ? H[(size_t)u * WD + lg] : 0.0f;
            acc = fmaf(w, h, acc);
        }
    }
    float r = dv * acc + dv * dv * self;
    if (act) {
        if (BIAS) r += bias[lg];
        if (RELU) r = fmaxf(r, 0.0f);
        if (HILO) {
            ushort h = f2bf(r);
            oh[(size_t)v * WD + lg] = h;
            ol[(size_t)v * WD + lg] = f2bf(r - bf2f(h));
        } else {
            out[(size_t)v * WD + lg] = r;
        }
    }
}

// width 256: one wave per node, float4 per lane
template <bool BIAS, bool RELU, bool HILO>
__global__ __launch_bounds__(256) void aggregate_v4_256_kernel(
    const float* __restrict__ H, const float* __restrict__ dinv,
    const int* __restrict__ row_ptr, const int* __restrict__ col_src,
    const float* __restrict__ bias, float* __restrict__ out,
    ushort* __restrict__ oh, ushort* __restrict__ ol) {
    int v = blockIdx.x * 4 + (threadIdx.x >> 6);
    int lane = threadIdx.x & 63;
    if (v >= NN) return;
    const float4* Hv = (const float4*)H;
    float dv = dinv[v];
    int beg = row_ptr[v], end = row_ptr[v + 1];
    float4 self = Hv[(size_t)v * 64 + lane];
    float4 acc = make_float4(0.f, 0.f, 0.f, 0.f);
    for (int cbeg = beg; cbeg < end; cbeg += 64) {
        int cnt = min(64, end - cbeg);
        int u_l = (lane < cnt) ? col_src[cbeg + lane] : 0;
        float w_l = (lane < cnt) ? dinv[u_l] : 0.0f;
        int e = 0;
        for (; e + 4 <= cnt; e += 4) {
            int u0 = __shfl(u_l, e + 0); float w0 = __shfl(w_l, e + 0);
            int u1 = __shfl(u_l, e + 1); float w1 = __shfl(w_l, e + 1);
            int u2 = __shfl(u_l, e + 2); float w2 = __shfl(w_l, e + 2);
            int u3 = __shfl(u_l, e + 3); float w3 = __shfl(w_l, e + 3);
            float4 h0 = Hv[(size_t)u0 * 64 + lane];
            float4 h1 = Hv[(size_t)u1 * 64 + lane];
            float4 h2 = Hv[(size_t)u2 * 64 + lane];
            float4 h3 = Hv[(size_t)u3 * 64 + lane];
            acc.x = fmaf(w0, h0.x, acc.x); acc.y = fmaf(w0, h0.y, acc.y);
            acc.z = fmaf(w0, h0.z, acc.z); acc.w = fmaf(w0, h0.w, acc.w);
            acc.x = fmaf(w1, h1.x, acc.x); acc.y = fmaf(w1, h1.y, acc.y);
            acc.z = fmaf(w1, h1.z, acc.z); acc.w = fmaf(w1, h1.w, acc.w);
            acc.x = fmaf(w2, h2.x, acc.x); acc.y = fmaf(w2, h2.y, acc.y);
            acc.z = fmaf(w2, h2.z, acc.z); acc.w = fmaf(w2, h2.w, acc.w);
            acc.x = fmaf(w3, h3.x, acc.x); acc.y = fmaf(w3, h3.y, acc.y);
            acc.z = fmaf(w3, h3.z, acc.z); acc.w = fmaf(w3, h3.w, acc.w);
        }
        for (; e < cnt; ++e) {
            int u = __shfl(u_l, e);
            float w = __shfl(w_l, e);
            float4 h = Hv[(size_t)u * 64 + lane];
            acc.x = fmaf(w, h.x, acc.x); acc.y = fmaf(w, h.y, acc.y);
            acc.z = fmaf(w, h.z, acc.z); acc.w = fmaf(w, h.w, acc.w);
        }
    }
    float dv2 = dv * dv;
    float4 r;
    r.x = fmaf(dv, acc.x, dv2 * self.x);
    r.y = fmaf(dv, acc.y, dv2 * self.y);
    r.z = fmaf(dv, acc.z, dv2 * self.z);
    r.w = fmaf(dv, acc.w, dv2 * self.w);
    if (BIAS) {
        float4 b = ((const float4*)bias)[lane];
        r.x += b.x; r.y += b.y; r.z += b.z; r.w += b.w;
    }
    if (RELU) {
        r.x = fmaxf(r.x, 0.f); r.y = fmaxf(r.y, 0.f);
        r.z = fmaxf(r.z, 0.f); r.w = fmaxf(r.w, 0.f);
    }
    if (HILO) {
        ushort4 hv, lv;
        hv.x = f2bf(r.x); lv.x = f2bf(r.x - bf2f(hv.x));
        hv.y = f2bf(r.y); lv.y = f2bf(r.y - bf2f(hv.y));
        hv.z = f2bf(r.z); lv.z = f2bf(r.z - bf2f(hv.z));
        hv.w = f2bf(r.w); lv.w = f2bf(r.w - bf2f(hv.w));
        *(ushort4*)&oh[(size_t)v * 256 + lane * 4] = hv;
        *(ushort4*)&ol[(size_t)v * 256 + lane * 4] = lv;
    } else {
        ((float4*)out)[(size_t)v * 64 + lane] = r;
    }
}

// ---------------- split-bf16 MFMA GEMM (32x32x16): C = A @ Wt^T ----------
// 128x128 tile, 4 waves in 2x2, each wave 2x2 of 32x32x16 MFMA tiles.
// fp32 emulated via 3 MFMAs per k-half: hi*hi + lo*hi + hi*lo.
// C/D layout (m74/m101 verified): col=lane&31, row=(reg&3)+8*(reg>>2)+4*(lane>>5).
// A/B frag: row=lane&31, k=(lane>>5)*8 + j (8 contiguous bf16 per lane).
// LDS rows padded to 40 shorts (80 B): 16B-aligned ds_read_b128, ~2-way banked.
// EPI: 0 = fp32 out; 1 = fp32 bias+relu; 2 = bf16 hi/lo out, bias+relu.

template <int EPI>
__global__ __launch_bounds__(256, 2) void gemm_bf16x3_32_kernel(
    const ushort* __restrict__ Ah, const ushort* __restrict__ Al,
    const ushort* __restrict__ Bh, const ushort* __restrict__ Bl,
    const float* __restrict__ bias, float* __restrict__ Cf,
    ushort* __restrict__ Ch, ushort* __restrict__ Cl,
    int M, int K, int Nd) {
    __shared__ short At[2][128][40];
    __shared__ short Bt[2][128][40];
    int tid = threadIdx.x;
    int bm = blockIdx.y * 128, bn = blockIdx.x * 128;
    int lane = tid & 63;
    int wave = tid >> 6;
    int l31 = lane & 31, q2 = lane >> 5;  // 0/1
    int wm = (wave & 1) * 64, wn = (wave >> 1) * 64;
    int sr = tid >> 1, sc = (tid & 1) * 16;  // staging: row, 16-short half

    f32x16 acc[2][2];
#pragma unroll
    for (int i = 0; i < 2; ++i)
#pragma unroll
        for (int j = 0; j < 2; ++j)
#pragma unroll
            for (int r = 0; r < 16; ++r) acc[i][j][r] = 0.0f;

    bool arow_ok = (bm + sr) < M;
    bool brow_ok = (bn + sr) < Nd;
    const ushort* Aph = Ah + (size_t)(bm + sr) * K + sc;
    const ushort* Apl = Al + (size_t)(bm + sr) * K + sc;
    const ushort* Bph = Bh + (size_t)(bn + sr) * K + sc;
    const ushort* Bpl = Bl + (size_t)(bn + sr) * K + sc;

    for (int k0 = 0; k0 < K; k0 += 32) {
        int4 z = {0, 0, 0, 0};
        int4 vah0 = z, vah1 = z, val0 = z, val1 = z;
        if (arow_ok) {
            vah0 = *(const int4*)(Aph + k0);
            vah1 = *(const int4*)(Aph + k0 + 8);
            val0 = *(const int4*)(Apl + k0);
            val1 = *(const int4*)(Apl + k0 + 8);
        }
        int4 vbh0 = z, vbh1 = z, vbl0 = z, vbl1 = z;
        if (brow_ok) {
            vbh0 = *(const int4*)(Bph + k0);
            vbh1 = *(const int4*)(Bph + k0 + 8);
            vbl0 = *(const int4*)(Bpl + k0);
            vbl1 = *(const int4*)(Bpl + k0 + 8);
        }
        __syncthreads();
        *(int4*)&At[0][sr][sc] = vah0;
        *(int4*)&At[0][sr][sc + 8] = vah1;
        *(int4*)&At[1][sr][sc] = val0;
        *(int4*)&At[1][sr][sc + 8] = val1;
        *(int4*)&Bt[0][sr][sc] = vbh0;
        *(int4*)&Bt[0][sr][sc + 8] = vbh1;
        *(int4*)&Bt[1][sr][sc] = vbl0;
        *(int4*)&Bt[1][sr][sc + 8] = vbl1;
        __syncthreads();

        // fragments: [i][kh]  kh = k-half (k0+0..15, k0+16..31); lane k-offset q2*8
        bf16x8 ah[2][2], al[2][2];
#pragma unroll
        for (int i = 0; i < 2; ++i) {
            const short* ar = &At[0][wm + i * 32 + l31][0];
            const short* arl = &At[1][wm + i * 32 + l31][0];
            ah[i][0] = *(const bf16x8*)(ar + q2 * 8);
            ah[i][1] = *(const bf16x8*)(ar + 16 + q2 * 8);
            al[i][0] = *(const bf16x8*)(arl + q2 * 8);
            al[i][1] = *(const bf16x8*)(arl + 16 + q2 * 8);
        }
#pragma unroll
        for (int j = 0; j < 2; ++j) {
            const short* br = &Bt[0][wn + j * 32 + l31][0];
            const short* brl = &Bt[1][wn + j * 32 + l31][0];
            bf16x8 bh0 = *(const bf16x8*)(br + q2 * 8);
            bf16x8 bh1 = *(const bf16x8*)(br + 16 + q2 * 8);
            bf16x8 bl0 = *(const bf16x8*)(brl + q2 * 8);
            bf16x8 bl1 = *(const bf16x8*)(brl + 16 + q2 * 8);
#pragma unroll
            for (int i = 0; i < 2; ++i) {
                acc[i][j] = __builtin_amdgcn_mfma_f32_32x32x16_bf16(ah[i][0], bh0, acc[i][j], 0, 0, 0);
                acc[i][j] = __builtin_amdgcn_mfma_f32_32x32x16_bf16(al[i][0], bh0, acc[i][j], 0, 0, 0);
                acc[i][j] = __builtin_amdgcn_mfma_f32_32x32x16_bf16(ah[i][0], bl0, acc[i][j], 0, 0, 0);
                acc[i][j] = __builtin_amdgcn_mfma_f32_32x32x16_bf16(ah[i][1], bh1, acc[i][j], 0, 0, 0);
                acc[i][j] = __builtin_amdgcn_mfma_f32_32x32x16_bf16(al[i][1], bh1, acc[i][j], 0, 0, 0);
                acc[i][j] = __builtin_amdgcn_mfma_f32_32x32x16_bf16(ah[i][1], bl1, acc[i][j], 0, 0, 0);
            }
        }
    }

    // epilogue: m = bm+wm+i*32+(r&3)+8*(r>>2)+4*q2, n = bn+wn+j*32+l31
#pragma unroll
    for (int j = 0; j < 2; ++j) {
        int n = bn + wn + j * 32 + l31;
        if (n >= Nd) continue;
        float bv = (EPI >= 1) ? bias[n] : 0.0f;
#pragma unroll
        for (int i = 0; i < 2; ++i) {
            int mb = bm + wm + i * 32 + 4 * q2;
#pragma unroll
            for (int r = 0; r < 16; ++r) {
                int m = mb + (r & 3) + 8 * (r >> 2);
                if (m >= M) continue;
                float v = acc[i][j][r];
                if (EPI >= 1) v = fmaxf(v + bv, 0.0f);
                if (EPI == 2) {
                    ushort h = f2bf(v);
                    Ch[(size_t)m * Nd + n] = h;
                    Cl[(size_t)m * Nd + n] = f2bf(v - bf2f(h));
                } else {
                    Cf[(size_t)m * Nd + n] = v;
                }
            }
        }
    }
}

// ---------------- fp32 GEMM, 64x64x16 tile, 4x4/thread (small layers) ----------------

template <bool BIASRELU>
__global__ __launch_bounds__(256, 4) void gemm_small_kernel(
    const float* __restrict__ A, const float* __restrict__ W,
    const float* __restrict__ bias, float* __restrict__ C,
    int M, int K, int Nd) {
    const int BK = 16;
    __shared__ float As[BK][68];
    __shared__ float Ws[BK][68];
    int bm = blockIdx.y * 64;
    int bn = blockIdx.x * 64;
    int tid = threadIdx.x;
    int tx = tid & 15;
    int ty = tid >> 4;

    int ar = tid >> 2;
    int ac = (tid & 3) * 4;
    int wcol = tid & 63;
    int wk0 = (tid >> 6) * 4;

    float acc[4][4];
#pragma unroll
    for (int i = 0; i < 4; ++i)
#pragma unroll
        for (int j = 0; j < 4; ++j) acc[i][j] = 0.0f;

    for (int k0 = 0; k0 < K; k0 += BK) {
        int gm = bm + ar;
        float a0 = 0.f, a1 = 0.f, a2 = 0.f, a3 = 0.f;
        if (gm < M) {
            const float* ap = &A[(size_t)gm * K];
            int gk = k0 + ac;
            a0 = (gk + 0 < K) ? ap[gk + 0] : 0.f;
            a1 = (gk + 1 < K) ? ap[gk + 1] : 0.f;
            a2 = (gk + 2 < K) ? ap[gk + 2] : 0.f;
            a3 = (gk + 3 < K) ? ap[gk + 3] : 0.f;
        }
        float w0 = 0.f, w1 = 0.f, w2 = 0.f, w3 = 0.f;
        if (bn + wcol < Nd) {
            int gk = k0 + wk0;
            w0 = (gk + 0 < K) ? W[(size_t)(gk + 0) * Nd + bn + wcol] : 0.f;
            w1 = (gk + 1 < K) ? W[(size_t)(gk + 1) * Nd + bn + wcol] : 0.f;
            w2 = (gk + 2 < K) ? W[(size_t)(gk + 2) * Nd + bn + wcol] : 0.f;
            w3 = (gk + 3 < K) ? W[(size_t)(gk + 3) * Nd + bn + wcol] : 0.f;
        }
        __syncthreads();
        As[ac + 0][ar] = a0;
        As[ac + 1][ar] = a1;
        As[ac + 2][ar] = a2;
        As[ac + 3][ar] = a3;
        Ws[wk0 + 0][wcol] = w0;
        Ws[wk0 + 1][wcol] = w1;
        Ws[wk0 + 2][wcol] = w2;
        Ws[wk0 + 3][wcol] = w3;
        __syncthreads();
#pragma unroll
        for (int kk = 0; kk < BK; ++kk) {
            float4 a = *(const float4*)&As[kk][ty * 4];
            float4 b = *(const float4*)&Ws[kk][tx * 4];
            float af[4] = {a.x, a.y, a.z, a.w};
            float bf[4] = {b.x, b.y, b.z, b.w};
#pragma unroll
            for (int i = 0; i < 4; ++i)
#pragma unroll
                for (int j = 0; j < 4; ++j) acc[i][j] = fmaf(af[i], bf[j], acc[i][j]);
        }
    }

    int col = bn + tx * 4;
    if (col >= Nd) return;
    float4 bi = make_float4(0.f, 0.f, 0.f, 0.f);
    if (BIASRELU) bi = *(const float4*)&bias[col];
#pragma unroll
    for (int i = 0; i < 4; ++i) {
        int m = bm + ty * 4 + i;
        if (m >= M) continue;
        float4 r = make_float4(acc[i][0], acc[i][1], acc[i][2], acc[i][3]);
        if (BIASRELU) {
            r.x = fmaxf(r.x + bi.x, 0.f); r.y = fmaxf(r.y + bi.y, 0.f);
            r.z = fmaxf(r.z + bi.z, 0.f); r.w = fmaxf(r.w + bi.w, 0.f);
        }
        *(float4*)&C[(size_t)m * Nd + col] = r;
    }
}

// ---------------- launch ----------------

extern "C" void kernel_launch(void* const* d_in, const int* in_sizes, int n_in,
                              void* d_out, int out_size, void* d_ws, size_t ws_size,
                              hipStream_t stream) {
    const float* x = (const float*)d_in[0];
    const int* ei = (const int*)d_in[1];
    const int* e_src = ei;
    const int* e_dst = ei + NE;
    const float* W1 = (const float*)d_in[2];
    const float* b1 = (const float*)d_in[3];
    const float* W2 = (const float*)d_in[4];
    const float* b2 = (const float*)d_in[5];
    const float* W3 = (const float*)d_in[6];
    const float* b3 = (const float*)d_in[7];
    const float* W4 = (const float*)d_in[8];
    const float* b4 = (const float*)d_in[9];
    const float* W5 = (const float*)d_in[10];
    const float* b5 = (const float*)d_in[11];
    const float* W6 = (const float*)d_in[12];
    const float* b6 = (const float*)d_in[13];
    float* out = (float*)d_out;

    // ---- workspace layout: 256B-aligned regions, liveness-checked ping-pong ----
    char* p = (char*)d_ws;
    auto take = [&p](size_t nbytes) {
        char* q = p;
        p += (nbytes + 255) & ~(size_t)255;
        return q;
    };
    char* RA = take((size_t)NN * 1024);   // 1 KB/node
    char* RB = take((size_t)NN * 1024);   // 1 KB/node
    char* RC = take((size_t)NN * 2048);   // 2 KB/node (X3 hi+lo @512)
    float* dinv = (float*)take((size_t)NN * 4);
    int* deg = (int*)take((size_t)NN * 4);
    int* row_ptr = (int*)take((size_t)(NN + 1) * 4);
    int* cursor = (int*)take((size_t)NN * 4);
    int* col_src = (int*)take((size_t)NE * 4);
    int* blk = (int*)take(256 * 4);
    ushort* W2th = (ushort*)take((size_t)64 * 256 * 2);
    ushort* W2tl = (ushort*)take((size_t)64 * 256 * 2);
    ushort* W3th = (ushort*)take((size_t)256 * 512 * 2);
    ushort* W3tl = (ushort*)take((size_t)256 * 512 * 2);
    ushort* W4th = (ushort*)take((size_t)512 * 256 * 2);
    ushort* W4tl = (ushort*)take((size_t)512 * 256 * 2);
    ushort* W5th = (ushort*)take((size_t)256 * 64 * 2);
    ushort* W5tl = (ushort*)take((size_t)256 * 64 * 2);

    // Buffer timeline (reads left, writes right; no overlap within a dispatch):
    //   agg1: x        -> A1f (RA)
    //   L1 :  A1f (RA) -> X1f (RB)
    //   agg2: X1f (RB) -> A2  (RC)
    //   L2 :  A2  (RC) -> X2f (RA)
    //   agg3: X2f (RA) -> A3  (RB)
    //   L3 :  A3  (RB) -> X3  (RC)
    //   L4 :  X3  (RC) -> H4f (RA)
    //   agg4: H4f (RA) -> X4 hi/lo (RB)   [NN*256*2*2B = 51.2 MB = RB exactly]
    //   L5 :  X4  (RB) -> H5f (RA)
    //   agg5: H5f (RA) -> X5f (RB)
    //   L6 :  X5f (RB) -> H6f (RA)
    //   agg6: H6f (RA) -> out
    float* A1f = (float*)RA;                       // NN x 35
    float* X1f = (float*)RB;                       // NN x 64
    ushort* A2h = (ushort*)RC;                     // NN x 64
    ushort* A2l = A2h + (size_t)NN * 64;
    float* X2f = (float*)RA;                       // NN x 256
    ushort* A3h = (ushort*)RB;                     // NN x 256
    ushort* A3l = A3h + (size_t)NN * 256;
    ushort* X3h = (ushort*)RC;                     // NN x 512
    ushort* X3l = X3h + (size_t)NN * 512;
    float* H4f = (float*)RA;                       // NN x 256
    ushort* X4h = (ushort*)RB;                     // NN x 256
    ushort* X4l = X4h + (size_t)NN * 256;
    float* H5f = (float*)RA;                       // NN x 64
    float* X5f = (float*)RB;                       // NN x 64
    float* H6f = (float*)RA;                       // NN x 16

    const int nblkN = (NN + 255) / 256;
    const int nblkE = (NE + 255) / 256;

    // CSR build
    zero_int_kernel<<<nblkN, 256, 0, stream>>>(deg, NN);
    count_deg_kernel<<<nblkE, 256, 0, stream>>>(e_dst, deg);
    dinv_kernel<<<nblkN, 256, 0, stream>>>(deg, dinv);
    scan_blocks_kernel<<<nblkN, 256, 0, stream>>>(deg, row_ptr, blk, NN);
    scan_sums_kernel<<<1, 256, 0, stream>>>(blk, nblkN, row_ptr, NN);
    scan_add_kernel<<<nblkN, 256, 0, stream>>>(row_ptr, blk, cursor, NN);
    scatter_kernel<<<nblkE, 256, 0, stream>>>(e_src, e_dst, cursor, col_src);

    // weight splits
    split_w_kernel<<<(64 * 256 + 255) / 256, 256, 0, stream>>>(W2, W2th, W2tl, 64, 256);
    split_w_kernel<<<(256 * 512 + 255) / 256, 256, 0, stream>>>(W3, W3th, W3tl, 256, 512);
    split_w_kernel<<<(512 * 256 + 255) / 256, 256, 0, stream>>>(W4, W4th, W4tl, 512, 256);
    split_w_kernel<<<(256 * 64 + 255) / 256, 256, 0, stream>>>(W5, W5th, W5tl, 256, 64);

    const int aggGrid64 = (NN + 3) / 4;
    const int aggGrid16 = (NN + 15) / 16;
    const int mrows = (NN + 127) / 128;  // 391

    // L1: agg(x,35) -> A1f ; X1 = relu(A1f@W1+b1) -> X1f (64)
    aggregate_scalar_kernel<35, 64, false, false, false><<<aggGrid64, 256, 0, stream>>>(
        x, dinv, row_ptr, col_src, nullptr, A1f, nullptr, nullptr);
    {
        dim3 g(1, (NN + 63) / 64);
        gemm_small_kernel<true><<<g, 256, 0, stream>>>(A1f, W1, b1, X1f, NN, 35, 64);
    }
    // L2: agg(X1,64) -> A2 hi/lo ; X2 = relu(A2@W2+b2) -> X2f (256 f32)
    aggregate_scalar_kernel<64, 64, false, false, true><<<aggGrid64, 256, 0, stream>>>(
        X1f, dinv, row_ptr, col_src, nullptr, nullptr, A2h, A2l);
    {
        dim3 g(2, mrows);
        gemm_bf16x3_32_kernel<1><<<g, 256, 0, stream>>>(A2h, A2l, W2th, W2tl, b2,
                                                        X2f, nullptr, nullptr, NN, 64, 256);
    }
    // L3: agg(X2,256) -> A3 hi/lo ; X3 = relu(A3@W3+b3) -> X3 hi/lo (512 bf16)
    aggregate_v4_256_kernel<false, false, true><<<aggGrid64, 256, 0, stream>>>(
        X2f, dinv, row_ptr, col_src, nullptr, nullptr, A3h, A3l);
    {
        dim3 g(4, mrows);
        gemm_bf16x3_32_kernel<2><<<g, 256, 0, stream>>>(A3h, A3l, W3th, W3tl, b3,
                                                        nullptr, X3h, X3l, NN, 256, 512);
    }
    // L4: H4 = X3@W4 -> H4f (256 f32) ; X4 = relu(S*H4+b4) -> X4 hi/lo (256 bf16)
    {
        dim3 g(2, mrows);
        gemm_bf16x3_32_kernel<0><<<g, 256, 0, stream>>>(X3h, X3l, W4th, W4tl, nullptr,
                                                        H4f, nullptr, nullptr, NN, 512, 256);
    }
    aggregate_v4_256_kernel<true, true, true><<<aggGrid64, 256, 0, stream>>>(
        H4f, dinv, row_ptr, col_src, b4, nullptr, X4h, X4l);
    // L5: H5 = X4@W5 -> H5f (64 f32) ; X5 = relu(S*H5+b5) -> X5f (64 f32)
    {
        dim3 g(1, mrows);
        gemm_bf16x3_32_kernel<0><<<g, 256, 0, stream>>>(X4h, X4l, W5th, W5tl, nullptr,
                                                        H5f, nullptr, nullptr, NN, 256, 64);
    }
    aggregate_scalar_kernel<64, 64, true, true, false><<<aggGrid64, 256, 0, stream>>>(
        H5f, dinv, row_ptr, col_src, b5, X5f, nullptr, nullptr);
    // L6: H6 = X5@W6 -> H6f (16 f32) ; out = S*H6 + b6
    {
        dim3 g(1, (NN + 63) / 64);
        gemm_small_kernel<false><<<g, 256, 0, stream>>>(X5f, W6, nullptr, H6f, NN, 64, 16);
    }
    aggregate_scalar_kernel<16, 16, true, false, false><<<aggGrid16, 256, 0, stream>>>(
        H6f, dinv, row_ptr, col_src, b6, out, nullptr, nullptr);
}

// Round 6
// 730.920 us; speedup vs baseline: 2.1156x; 1.0232x over previous
//
#include <hip/hip_runtime.h>

#define NN 50000
#define NE 800000

typedef __attribute__((ext_vector_type(8))) short bf16x8;
typedef __attribute__((ext_vector_type(16))) float f32x16;

__device__ inline ushort f2bf(float f) {
    union { float f; unsigned u; } v; v.f = f;
    unsigned r = (v.u + 0x7FFFu + ((v.u >> 16) & 1u)) >> 16;  // RNE
    return (ushort)r;
}
__device__ inline float bf2f(ushort h) {
    union { float f; unsigned u; } v; v.u = ((unsigned)h) << 16;
    return v.f;
}

// ---------------- CSR build ----------------

__global__ __launch_bounds__(256) void zero_int_kernel(int* __restrict__ p, int n) {
    int i = blockIdx.x * 256 + threadIdx.x;
    if (i < n) p[i] = 0;
}

__global__ __launch_bounds__(256) void count_deg_kernel(const int* __restrict__ dst,
                                                        int* __restrict__ deg) {
    int e = blockIdx.x * 256 + threadIdx.x;
    if (e < NE) atomicAdd(&deg[dst[e]], 1);
}

__global__ __launch_bounds__(256) void dinv_kernel(const int* __restrict__ deg,
                                                   float* __restrict__ dinv) {
    int v = blockIdx.x * 256 + threadIdx.x;
    if (v < NN) dinv[v] = rsqrtf((float)(deg[v] + 1));  // +1 self loop
}

__global__ __launch_bounds__(256) void scan_blocks_kernel(const int* __restrict__ deg,
                                                          int* __restrict__ out,
                                                          int* __restrict__ blk, int n) {
    __shared__ int s[256];
    int tid = threadIdx.x;
    int i = blockIdx.x * 256 + tid;
    int v = (i < n) ? deg[i] : 0;
    s[tid] = v;
    __syncthreads();
    for (int off = 1; off < 256; off <<= 1) {
        int t = (tid >= off) ? s[tid - off] : 0;
        __syncthreads();
        s[tid] += t;
        __syncthreads();
    }
    if (i < n) out[i] = s[tid] - v;
    if (tid == 255) blk[blockIdx.x] = s[255];
}

__global__ __launch_bounds__(256) void scan_sums_kernel(int* __restrict__ blk, int nb,
                                                        int* __restrict__ row_ptr, int n) {
    __shared__ int s[256];
    int tid = threadIdx.x;
    int v = (tid < nb) ? blk[tid] : 0;
    s[tid] = v;
    __syncthreads();
    for (int off = 1; off < 256; off <<= 1) {
        int t = (tid >= off) ? s[tid - off] : 0;
        __syncthreads();
        s[tid] += t;
        __syncthreads();
    }
    if (tid < nb) blk[tid] = s[tid] - v;
    if (tid == 255) row_ptr[n] = s[255];
}

__global__ __launch_bounds__(256) void scan_add_kernel(int* __restrict__ row_ptr,
                                                       const int* __restrict__ blk,
                                                       int* __restrict__ cursor, int n) {
    int i = blockIdx.x * 256 + threadIdx.x;
    if (i < n) {
        int r = row_ptr[i] + blk[blockIdx.x];
        row_ptr[i] = r;
        cursor[i] = r;
    }
}

__global__ __launch_bounds__(256) void scatter_kernel(const int* __restrict__ src,
                                                      const int* __restrict__ dst,
                                                      int* __restrict__ cursor,
                                                      int* __restrict__ col_src) {
    int e = blockIdx.x * 256 + threadIdx.x;
    if (e < NE) {
        int d = dst[e];
        int pos = atomicAdd(&cursor[d], 1);
        col_src[pos] = src[e];
    }
}

// ---------------- weight split + transpose: W[K][Nd] fp32 -> Wt_hi/Wt_lo [Nd][K] bf16 ----

__global__ __launch_bounds__(256) void split_w_kernel(const float* __restrict__ W,
                                                      ushort* __restrict__ Wth,
                                                      ushort* __restrict__ Wtl,
                                                      int K, int Nd) {
    int i = blockIdx.x * 256 + threadIdx.x;
    if (i >= K * Nd) return;
    int k = i / Nd, n = i - k * Nd;
    float w = W[i];
    ushort h = f2bf(w);
    Wth[(size_t)n * K + k] = h;
    Wtl[(size_t)n * K + k] = f2bf(w - bf2f(h));
}

// ------- aggregation: out[v] = dv*sum du*H[u] + dv^2*H[v] (+bias,relu | hilo) -------

// scalar variant (odd widths, e.g. 35): GS lanes/node, 1 float per lane, unroll 8
template <int WD, int GS, bool BIAS, bool RELU, bool HILO>
__global__ __launch_bounds__(256) void aggregate_scalar_kernel(
    const float* __restrict__ H, const float* __restrict__ dinv,
    const int* __restrict__ row_ptr, const int* __restrict__ col_src,
    const float* __restrict__ bias, float* __restrict__ out,
    ushort* __restrict__ oh, ushort* __restrict__ ol) {
    const int NPB = 256 / GS;
    int v = blockIdx.x * NPB + (threadIdx.x / GS);
    int lg = threadIdx.x & (GS - 1);
    if (v >= NN) return;
    bool act = (WD == GS) ? true : (lg < WD);
    float dv = dinv[v];
    int beg = row_ptr[v], end = row_ptr[v + 1];
    float self = act ? H[(size_t)v * WD + lg] : 0.0f;
    float acc = 0.0f;
    for (int cbeg = beg; cbeg < end; cbeg += GS) {
        int cnt = min(GS, end - cbeg);
        int u_l = (lg < cnt) ? col_src[cbeg + lg] : 0;
        float w_l = (lg < cnt) ? dinv[u_l] : 0.0f;
        int e = 0;
        for (; e + 8 <= cnt; e += 8) {
            int u[8]; float w[8]; float h[8];
#pragma unroll
            for (int t = 0; t < 8; ++t) {
                u[t] = __shfl(u_l, e + t, GS);
                w[t] = __shfl(w_l, e + t, GS);
            }
#pragma unroll
            for (int t = 0; t < 8; ++t) h[t] = act ? H[(size_t)u[t] * WD + lg] : 0.0f;
#pragma unroll
            for (int t = 0; t < 8; ++t) acc = fmaf(w[t], h[t], acc);
        }
        for (; e < cnt; ++e) {
            int u = __shfl(u_l, e, GS);
            float w = __shfl(w_l, e, GS);
            float h = act ? H[(size_t)u * WD + lg] : 0.0f;
            acc = fmaf(w, h, acc);
        }
    }
    float r = dv * acc + dv * dv * self;
    if (act) {
        if (BIAS) r += bias[lg];
        if (RELU) r = fmaxf(r, 0.0f);
        if (HILO) {
            ushort h = f2bf(r);
            oh[(size_t)v * WD + lg] = h;
            ol[(size_t)v * WD + lg] = f2bf(r - bf2f(h));
        } else {
            out[(size_t)v * WD + lg] = r;
        }
    }
}

// vectorized variant: GS = WD/4 lanes/node, one float4 per lane.
// WD=256 -> GS=64 (1 node/wave), WD=64 -> GS=16 (4 nodes/wave), WD=16 -> GS=4.
template <int WD, bool BIAS, bool RELU, bool HILO>
__global__ __launch_bounds__(256) void aggregate_vec_kernel(
    const float* __restrict__ H, const float* __restrict__ dinv,
    const int* __restrict__ row_ptr, const int* __restrict__ col_src,
    const float* __restrict__ bias, float* __restrict__ out,
    ushort* __restrict__ oh, ushort* __restrict__ ol) {
    const int GS = WD / 4;
    const int NPB = 256 / GS;
    int v = blockIdx.x * NPB + (threadIdx.x / GS);
    int lg = threadIdx.x & (GS - 1);
    if (v >= NN) return;
    const float4* Hv = (const float4*)H;
    float dv = dinv[v];
    int beg = row_ptr[v], end = row_ptr[v + 1];
    float4 self = Hv[(size_t)v * GS + lg];
    float4 acc = make_float4(0.f, 0.f, 0.f, 0.f);
    for (int cbeg = beg; cbeg < end; cbeg += GS) {
        int cnt = min(GS, end - cbeg);
        int u_l = (lg < cnt) ? col_src[cbeg + lg] : 0;
        float w_l = (lg < cnt) ? dinv[u_l] : 0.0f;
        int e = 0;
        for (; e + 4 <= cnt; e += 4) {
            int u0 = __shfl(u_l, e + 0, GS); float w0 = __shfl(w_l, e + 0, GS);
            int u1 = __shfl(u_l, e + 1, GS); float w1 = __shfl(w_l, e + 1, GS);
            int u2 = __shfl(u_l, e + 2, GS); float w2 = __shfl(w_l, e + 2, GS);
            int u3 = __shfl(u_l, e + 3, GS); float w3 = __shfl(w_l, e + 3, GS);
            float4 h0 = Hv[(size_t)u0 * GS + lg];
            float4 h1 = Hv[(size_t)u1 * GS + lg];
            float4 h2 = Hv[(size_t)u2 * GS + lg];
            float4 h3 = Hv[(size_t)u3 * GS + lg];
            acc.x = fmaf(w0, h0.x, acc.x); acc.y = fmaf(w0, h0.y, acc.y);
            acc.z = fmaf(w0, h0.z, acc.z); acc.w = fmaf(w0, h0.w, acc.w);
            acc.x = fmaf(w1, h1.x, acc.x); acc.y = fmaf(w1, h1.y, acc.y);
            acc.z = fmaf(w1, h1.z, acc.z); acc.w = fmaf(w1, h1.w, acc.w);
            acc.x = fmaf(w2, h2.x, acc.x); acc.y = fmaf(w2, h2.y, acc.y);
            acc.z = fmaf(w2, h2.z, acc.z); acc.w = fmaf(w2, h2.w, acc.w);
            acc.x = fmaf(w3, h3.x, acc.x); acc.y = fmaf(w3, h3.y, acc.y);
            acc.z = fmaf(w3, h3.z, acc.z); acc.w = fmaf(w3, h3.w, acc.w);
        }
        for (; e < cnt; ++e) {
            int u = __shfl(u_l, e, GS);
            float w = __shfl(w_l, e, GS);
            float4 h = Hv[(size_t)u * GS + lg];
            acc.x = fmaf(w, h.x, acc.x); acc.y = fmaf(w, h.y, acc.y);
            acc.z = fmaf(w, h.z, acc.z); acc.w = fmaf(w, h.w, acc.w);
        }
    }
    float dv2 = dv * dv;
    float4 r;
    r.x = fmaf(dv, acc.x, dv2 * self.x);
    r.y = fmaf(dv, acc.y, dv2 * self.y);
    r.z = fmaf(dv, acc.z, dv2 * self.z);
    r.w = fmaf(dv, acc.w, dv2 * self.w);
    if (BIAS) {
        float4 b = ((const float4*)bias)[lg];
        r.x += b.x; r.y += b.y; r.z += b.z; r.w += b.w;
    }
    if (RELU) {
        r.x = fmaxf(r.x, 0.f); r.y = fmaxf(r.y, 0.f);
        r.z = fmaxf(r.z, 0.f); r.w = fmaxf(r.w, 0.f);
    }
    if (HILO) {
        ushort4 hv, lv;
        hv.x = f2bf(r.x); lv.x = f2bf(r.x - bf2f(hv.x));
        hv.y = f2bf(r.y); lv.y = f2bf(r.y - bf2f(hv.y));
        hv.z = f2bf(r.z); lv.z = f2bf(r.z - bf2f(hv.z));
        hv.w = f2bf(r.w); lv.w = f2bf(r.w - bf2f(hv.w));
        *(ushort4*)&oh[(size_t)v * WD + lg * 4] = hv;
        *(ushort4*)&ol[(size_t)v * WD + lg * 4] = lv;
    } else {
        ((float4*)out)[(size_t)v * GS + lg] = r;
    }
}

// ---------------- split-bf16 MFMA GEMM (32x32x16): C = A @ Wt^T ----------
// 128x128 tile, 4 waves in 2x2, each wave 2x2 of 32x32x16 MFMA tiles.
// fp32 emulated via 3 MFMAs per k-half: hi*hi + lo*hi + hi*lo.
// C/D layout (m74/m101 verified): col=lane&31, row=(reg&3)+8*(reg>>2)+4*(lane>>5).
// EPI: 0 = fp32 out; 1 = fp32 bias+relu; 2 = bf16 hi/lo out, bias+relu.

template <int EPI>
__global__ __launch_bounds__(256, 2) void gemm_bf16x3_32_kernel(
    const ushort* __restrict__ Ah, const ushort* __restrict__ Al,
    const ushort* __restrict__ Bh, const ushort* __restrict__ Bl,
    const float* __restrict__ bias, float* __restrict__ Cf,
    ushort* __restrict__ Ch, ushort* __restrict__ Cl,
    int M, int K, int Nd) {
    __shared__ short At[2][128][40];
    __shared__ short Bt[2][128][40];
    int tid = threadIdx.x;
    int bm = blockIdx.y * 128, bn = blockIdx.x * 128;
    int lane = tid & 63;
    int wave = tid >> 6;
    int l31 = lane & 31, q2 = lane >> 5;  // 0/1
    int wm = (wave & 1) * 64, wn = (wave >> 1) * 64;
    int sr = tid >> 1, sc = (tid & 1) * 16;  // staging: row, 16-short half

    f32x16 acc[2][2];
#pragma unroll
    for (int i = 0; i < 2; ++i)
#pragma unroll
        for (int j = 0; j < 2; ++j)
#pragma unroll
            for (int r = 0; r < 16; ++r) acc[i][j][r] = 0.0f;

    bool arow_ok = (bm + sr) < M;
    bool brow_ok = (bn + sr) < Nd;
    const ushort* Aph = Ah + (size_t)(bm + sr) * K + sc;
    const ushort* Apl = Al + (size_t)(bm + sr) * K + sc;
    const ushort* Bph = Bh + (size_t)(bn + sr) * K + sc;
    const ushort* Bpl = Bl + (size_t)(bn + sr) * K + sc;

    for (int k0 = 0; k0 < K; k0 += 32) {
        int4 z = {0, 0, 0, 0};
        int4 vah0 = z, vah1 = z, val0 = z, val1 = z;
        if (arow_ok) {
            vah0 = *(const int4*)(Aph + k0);
            vah1 = *(const int4*)(Aph + k0 + 8);
            val0 = *(const int4*)(Apl + k0);
            val1 = *(const int4*)(Apl + k0 + 8);
        }
        int4 vbh0 = z, vbh1 = z, vbl0 = z, vbl1 = z;
        if (brow_ok) {
            vbh0 = *(const int4*)(Bph + k0);
            vbh1 = *(const int4*)(Bph + k0 + 8);
            vbl0 = *(const int4*)(Bpl + k0);
            vbl1 = *(const int4*)(Bpl + k0 + 8);
        }
        __syncthreads();
        *(int4*)&At[0][sr][sc] = vah0;
        *(int4*)&At[0][sr][sc + 8] = vah1;
        *(int4*)&At[1][sr][sc] = val0;
        *(int4*)&At[1][sr][sc + 8] = val1;
        *(int4*)&Bt[0][sr][sc] = vbh0;
        *(int4*)&Bt[0][sr][sc + 8] = vbh1;
        *(int4*)&Bt[1][sr][sc] = vbl0;
        *(int4*)&Bt[1][sr][sc + 8] = vbl1;
        __syncthreads();

        bf16x8 ah[2][2], al[2][2];
#pragma unroll
        for (int i = 0; i < 2; ++i) {
            const short* ar = &At[0][wm + i * 32 + l31][0];
            const short* arl = &At[1][wm + i * 32 + l31][0];
            ah[i][0] = *(const bf16x8*)(ar + q2 * 8);
            ah[i][1] = *(const bf16x8*)(ar + 16 + q2 * 8);
            al[i][0] = *(const bf16x8*)(arl + q2 * 8);
            al[i][1] = *(const bf16x8*)(arl + 16 + q2 * 8);
        }
#pragma unroll
        for (int j = 0; j < 2; ++j) {
            const short* br = &Bt[0][wn + j * 32 + l31][0];
            const short* brl = &Bt[1][wn + j * 32 + l31][0];
            bf16x8 bh0 = *(const bf16x8*)(br + q2 * 8);
            bf16x8 bh1 = *(const bf16x8*)(br + 16 + q2 * 8);
            bf16x8 bl0 = *(const bf16x8*)(brl + q2 * 8);
            bf16x8 bl1 = *(const bf16x8*)(brl + 16 + q2 * 8);
#pragma unroll
            for (int i = 0; i < 2; ++i) {
                acc[i][j] = __builtin_amdgcn_mfma_f32_32x32x16_bf16(ah[i][0], bh0, acc[i][j], 0, 0, 0);
                acc[i][j] = __builtin_amdgcn_mfma_f32_32x32x16_bf16(al[i][0], bh0, acc[i][j], 0, 0, 0);
                acc[i][j] = __builtin_amdgcn_mfma_f32_32x32x16_bf16(ah[i][0], bl0, acc[i][j], 0, 0, 0);
                acc[i][j] = __builtin_amdgcn_mfma_f32_32x32x16_bf16(ah[i][1], bh1, acc[i][j], 0, 0, 0);
                acc[i][j] = __builtin_amdgcn_mfma_f32_32x32x16_bf16(al[i][1], bh1, acc[i][j], 0, 0, 0);
                acc[i][j] = __builtin_amdgcn_mfma_f32_32x32x16_bf16(ah[i][1], bl1, acc[i][j], 0, 0, 0);
            }
        }
    }

    // epilogue: m = bm+wm+i*32+(r&3)+8*(r>>2)+4*q2, n = bn+wn+j*32+l31
#pragma unroll
    for (int j = 0; j < 2; ++j) {
        int n = bn + wn + j * 32 + l31;
        if (n >= Nd) continue;
        float bv = (EPI >= 1) ? bias[n] : 0.0f;
#pragma unroll
        for (int i = 0; i < 2; ++i) {
            int mb = bm + wm + i * 32 + 4 * q2;
#pragma unroll
            for (int r = 0; r < 16; ++r) {
                int m = mb + (r & 3) + 8 * (r >> 2);
                if (m >= M) continue;
                float v = acc[i][j][r];
                if (EPI >= 1) v = fmaxf(v + bv, 0.0f);
                if (EPI == 2) {
                    ushort h = f2bf(v);
                    Ch[(size_t)m * Nd + n] = h;
                    Cl[(size_t)m * Nd + n] = f2bf(v - bf2f(h));
                } else {
                    Cf[(size_t)m * Nd + n] = v;
                }
            }
        }
    }
}

// ---------------- fp32 GEMM, 64x64x16 tile, 4x4/thread (small layers) ----------------

template <bool BIASRELU>
__global__ __launch_bounds__(256, 4) void gemm_small_kernel(
    const float* __restrict__ A, const float* __restrict__ W,
    const float* __restrict__ bias, float* __restrict__ C,
    int M, int K, int Nd) {
    const int BK = 16;
    __shared__ float As[BK][68];
    __shared__ float Ws[BK][68];
    int bm = blockIdx.y * 64;
    int bn = blockIdx.x * 64;
    int tid = threadIdx.x;
    int tx = tid & 15;
    int ty = tid >> 4;

    int ar = tid >> 2;
    int ac = (tid & 3) * 4;
    int wcol = tid & 63;
    int wk0 = (tid >> 6) * 4;

    float acc[4][4];
#pragma unroll
    for (int i = 0; i < 4; ++i)
#pragma unroll
        for (int j = 0; j < 4; ++j) acc[i][j] = 0.0f;

    for (int k0 = 0; k0 < K; k0 += BK) {
        int gm = bm + ar;
        float a0 = 0.f, a1 = 0.f, a2 = 0.f, a3 = 0.f;
        if (gm < M) {
            const float* ap = &A[(size_t)gm * K];
            int gk = k0 + ac;
            a0 = (gk + 0 < K) ? ap[gk + 0] : 0.f;
            a1 = (gk + 1 < K) ? ap[gk + 1] : 0.f;
            a2 = (gk + 2 < K) ? ap[gk + 2] : 0.f;
            a3 = (gk + 3 < K) ? ap[gk + 3] : 0.f;
        }
        float w0 = 0.f, w1 = 0.f, w2 = 0.f, w3 = 0.f;
        if (bn + wcol < Nd) {
            int gk = k0 + wk0;
            w0 = (gk + 0 < K) ? W[(size_t)(gk + 0) * Nd + bn + wcol] : 0.f;
            w1 = (gk + 1 < K) ? W[(size_t)(gk + 1) * Nd + bn + wcol] : 0.f;
            w2 = (gk + 2 < K) ? W[(size_t)(gk + 2) * Nd + bn + wcol] : 0.f;
            w3 = (gk + 3 < K) ? W[(size_t)(gk + 3) * Nd + bn + wcol] : 0.f;
        }
        __syncthreads();
        As[ac + 0][ar] = a0;
        As[ac + 1][ar] = a1;
        As[ac + 2][ar] = a2;
        As[ac + 3][ar] = a3;
        Ws[wk0 + 0][wcol] = w0;
        Ws[wk0 + 1][wcol] = w1;
        Ws[wk0 + 2][wcol] = w2;
        Ws[wk0 + 3][wcol] = w3;
        __syncthreads();
#pragma unroll
        for (int kk = 0; kk < BK; ++kk) {
            float4 a = *(const float4*)&As[kk][ty * 4];
            float4 b = *(const float4*)&Ws[kk][tx * 4];
            float af[4] = {a.x, a.y, a.z, a.w};
            float bf[4] = {b.x, b.y, b.z, b.w};
#pragma unroll
            for (int i = 0; i < 4; ++i)
#pragma unroll
                for (int j = 0; j < 4; ++j) acc[i][j] = fmaf(af[i], bf[j], acc[i][j]);
        }
    }

    int col = bn + tx * 4;
    if (col >= Nd) return;
    float4 bi = make_float4(0.f, 0.f, 0.f, 0.f);
    if (BIASRELU) bi = *(const float4*)&bias[col];
#pragma unroll
    for (int i = 0; i < 4; ++i) {
        int m = bm + ty * 4 + i;
        if (m >= M) continue;
        float4 r = make_float4(acc[i][0], acc[i][1], acc[i][2], acc[i][3]);
        if (BIASRELU) {
            r.x = fmaxf(r.x + bi.x, 0.f); r.y = fmaxf(r.y + bi.y, 0.f);
            r.z = fmaxf(r.z + bi.z, 0.f); r.w = fmaxf(r.w + bi.w, 0.f);
        }
        *(float4*)&C[(size_t)m * Nd + col] = r;
    }
}

// ---------------- launch ----------------

extern "C" void kernel_launch(void* const* d_in, const int* in_sizes, int n_in,
                              void* d_out, int out_size, void* d_ws, size_t ws_size,
                              hipStream_t stream) {
    const float* x = (const float*)d_in[0];
    const int* ei = (const int*)d_in[1];
    const int* e_src = ei;
    const int* e_dst = ei + NE;
    const float* W1 = (const float*)d_in[2];
    const float* b1 = (const float*)d_in[3];
    const float* W2 = (const float*)d_in[4];
    const float* b2 = (const float*)d_in[5];
    const float* W3 = (const float*)d_in[6];
    const float* b3 = (const float*)d_in[7];
    const float* W4 = (const float*)d_in[8];
    const float* b4 = (const float*)d_in[9];
    const float* W5 = (const float*)d_in[10];
    const float* b5 = (const float*)d_in[11];
    const float* W6 = (const float*)d_in[12];
    const float* b6 = (const float*)d_in[13];
    float* out = (float*)d_out;

    // ---- workspace layout: 256B-aligned regions, liveness-checked ping-pong ----
    char* p = (char*)d_ws;
    auto take = [&p](size_t nbytes) {
        char* q = p;
        p += (nbytes + 255) & ~(size_t)255;
        return q;
    };
    char* RA = take((size_t)NN * 1024);   // 1 KB/node
    char* RB = take((size_t)NN * 1024);   // 1 KB/node
    char* RC = take((size_t)NN * 2048);   // 2 KB/node (X3 hi+lo @512)
    float* dinv = (float*)take((size_t)NN * 4);
    int* deg = (int*)take((size_t)NN * 4);
    int* row_ptr = (int*)take((size_t)(NN + 1) * 4);
    int* cursor = (int*)take((size_t)NN * 4);
    int* col_src = (int*)take((size_t)NE * 4);
    int* blk = (int*)take(256 * 4);
    ushort* W2th = (ushort*)take((size_t)64 * 256 * 2);
    ushort* W2tl = (ushort*)take((size_t)64 * 256 * 2);
    ushort* W3th = (ushort*)take((size_t)256 * 512 * 2);
    ushort* W3tl = (ushort*)take((size_t)256 * 512 * 2);
    ushort* W4th = (ushort*)take((size_t)512 * 256 * 2);
    ushort* W4tl = (ushort*)take((size_t)512 * 256 * 2);
    ushort* W5th = (ushort*)take((size_t)256 * 64 * 2);
    ushort* W5tl = (ushort*)take((size_t)256 * 64 * 2);

    // Buffer timeline (reads left, writes right; no overlap within a dispatch):
    //   agg1: x        -> A1f (RA)
    //   L1 :  A1f (RA) -> X1f (RB)
    //   agg2: X1f (RB) -> A2  (RC)
    //   L2 :  A2  (RC) -> X2f (RA)
    //   agg3: X2f (RA) -> A3  (RB)
    //   L3 :  A3  (RB) -> X3  (RC)
    //   L4 :  X3  (RC) -> H4f (RA)
    //   agg4: H4f (RA) -> X4 hi/lo (RB)
    //   L5 :  X4  (RB) -> H5f (RA)
    //   agg5: H5f (RA) -> X5f (RB)
    //   L6 :  X5f (RB) -> H6f (RA)
    //   agg6: H6f (RA) -> out
    float* A1f = (float*)RA;                       // NN x 35
    float* X1f = (float*)RB;                       // NN x 64
    ushort* A2h = (ushort*)RC;                     // NN x 64
    ushort* A2l = A2h + (size_t)NN * 64;
    float* X2f = (float*)RA;                       // NN x 256
    ushort* A3h = (ushort*)RB;                     // NN x 256
    ushort* A3l = A3h + (size_t)NN * 256;
    ushort* X3h = (ushort*)RC;                     // NN x 512
    ushort* X3l = X3h + (size_t)NN * 512;
    float* H4f = (float*)RA;                       // NN x 256
    ushort* X4h = (ushort*)RB;                     // NN x 256
    ushort* X4l = X4h + (size_t)NN * 256;
    float* H5f = (float*)RA;                       // NN x 64
    float* X5f = (float*)RB;                       // NN x 64
    float* H6f = (float*)RA;                       // NN x 16

    const int nblkN = (NN + 255) / 256;
    const int nblkE = (NE + 255) / 256;

    // CSR build
    zero_int_kernel<<<nblkN, 256, 0, stream>>>(deg, NN);
    count_deg_kernel<<<nblkE, 256, 0, stream>>>(e_dst, deg);
    dinv_kernel<<<nblkN, 256, 0, stream>>>(deg, dinv);
    scan_blocks_kernel<<<nblkN, 256, 0, stream>>>(deg, row_ptr, blk, NN);
    scan_sums_kernel<<<1, 256, 0, stream>>>(blk, nblkN, row_ptr, NN);
    scan_add_kernel<<<nblkN, 256, 0, stream>>>(row_ptr, blk, cursor, NN);
    scatter_kernel<<<nblkE, 256, 0, stream>>>(e_src, e_dst, cursor, col_src);

    // weight splits
    split_w_kernel<<<(64 * 256 + 255) / 256, 256, 0, stream>>>(W2, W2th, W2tl, 64, 256);
    split_w_kernel<<<(256 * 512 + 255) / 256, 256, 0, stream>>>(W3, W3th, W3tl, 256, 512);
    split_w_kernel<<<(512 * 256 + 255) / 256, 256, 0, stream>>>(W4, W4th, W4tl, 512, 256);
    split_w_kernel<<<(256 * 64 + 255) / 256, 256, 0, stream>>>(W5, W5th, W5tl, 256, 64);

    const int aggGrid256 = (NN + 3) / 4;    // WD=256: 4 nodes/block
    const int aggGrid64v = (NN + 15) / 16;  // WD=64 vec: 16 nodes/block
    const int aggGrid16v = (NN + 63) / 64;  // WD=16 vec: 64 nodes/block
    const int aggGrid35 = (NN + 3) / 4;     // WD=35 scalar: 4 nodes/block
    const int mrows = (NN + 127) / 128;     // 391

    // L1: agg(x,35) -> A1f ; X1 = relu(A1f@W1+b1) -> X1f (64)
    aggregate_scalar_kernel<35, 64, false, false, false><<<aggGrid35, 256, 0, stream>>>(
        x, dinv, row_ptr, col_src, nullptr, A1f, nullptr, nullptr);
    {
        dim3 g(1, (NN + 63) / 64);
        gemm_small_kernel<true><<<g, 256, 0, stream>>>(A1f, W1, b1, X1f, NN, 35, 64);
    }
    // L2: agg(X1,64) -> A2 hi/lo ; X2 = relu(A2@W2+b2) -> X2f (256 f32)
    aggregate_vec_kernel<64, false, false, true><<<aggGrid64v, 256, 0, stream>>>(
        X1f, dinv, row_ptr, col_src, nullptr, nullptr, A2h, A2l);
    {
        dim3 g(2, mrows);
        gemm_bf16x3_32_kernel<1><<<g, 256, 0, stream>>>(A2h, A2l, W2th, W2tl, b2,
                                                        X2f, nullptr, nullptr, NN, 64, 256);
    }
    // L3: agg(X2,256) -> A3 hi/lo ; X3 = relu(A3@W3+b3) -> X3 hi/lo (512 bf16)
    aggregate_vec_kernel<256, false, false, true><<<aggGrid256, 256, 0, stream>>>(
        X2f, dinv, row_ptr, col_src, nullptr, nullptr, A3h, A3l);
    {
        dim3 g(4, mrows);
        gemm_bf16x3_32_kernel<2><<<g, 256, 0, stream>>>(A3h, A3l, W3th, W3tl, b3,
                                                        nullptr, X3h, X3l, NN, 256, 512);
    }
    // L4: H4 = X3@W4 -> H4f (256 f32) ; X4 = relu(S*H4+b4) -> X4 hi/lo (256 bf16)
    {
        dim3 g(2, mrows);
        gemm_bf16x3_32_kernel<0><<<g, 256, 0, stream>>>(X3h, X3l, W4th, W4tl, nullptr,
                                                        H4f, nullptr, nullptr, NN, 512, 256);
    }
    aggregate_vec_kernel<256, true, true, true><<<aggGrid256, 256, 0, stream>>>(
        H4f, dinv, row_ptr, col_src, b4, nullptr, X4h, X4l);
    // L5: H5 = X4@W5 -> H5f (64 f32) ; X5 = relu(S*H5+b5) -> X5f (64 f32)
    {
        dim3 g(1, mrows);
        gemm_bf16x3_32_kernel<0><<<g, 256, 0, stream>>>(X4h, X4l, W5th, W5tl, nullptr,
                                                        H5f, nullptr, nullptr, NN, 256, 64);
    }
    aggregate_vec_kernel<64, true, true, false><<<aggGrid64v, 256, 0, stream>>>(
        H5f, dinv, row_ptr, col_src, b5, X5f, nullptr, nullptr);
    // L6: H6 = X5@W6 -> H6f (16 f32) ; out = S*H6 + b6
    {
        dim3 g(1, (NN + 63) / 64);
        gemm_small_kernel<false><<<g, 256, 0, stream>>>(X5f, W6, nullptr, H6f, NN, 64, 16);
    }
    aggregate_vec_kernel<16, true, false, false><<<aggGrid16v, 256, 0, stream>>>(
        H6f, dinv, row_ptr, col_src, b6, out, nullptr, nullptr);
}

// Round 7
// 720.309 us; speedup vs baseline: 2.1468x; 1.0147x over previous
//
#include <hip/hip_runtime.h>

#define NN 50000
#define NE 800000

typedef __attribute__((ext_vector_type(8))) short bf16x8;
typedef __attribute__((ext_vector_type(16))) float f32x16;

__device__ inline ushort f2bf(float f) {
    union { float f; unsigned u; } v; v.f = f;
    unsigned r = (v.u + 0x7FFFu + ((v.u >> 16) & 1u)) >> 16;  // RNE
    return (ushort)r;
}
__device__ inline float bf2f(ushort h) {
    union { float f; unsigned u; } v; v.u = ((unsigned)h) << 16;
    return v.f;
}

// ---------------- CSR build ----------------

__global__ __launch_bounds__(256) void zero_int_kernel(int* __restrict__ p, int n) {
    int i = blockIdx.x * 256 + threadIdx.x;
    if (i < n) p[i] = 0;
}

__global__ __launch_bounds__(256) void count_deg_kernel(const int* __restrict__ dst,
                                                        int* __restrict__ deg) {
    int e = blockIdx.x * 256 + threadIdx.x;
    if (e < NE) atomicAdd(&deg[dst[e]], 1);
}

// block-level exclusive scan of deg -> out, block totals -> blk; also dinv = rsqrt(deg+1)
__global__ __launch_bounds__(256) void scan_blocks_kernel(const int* __restrict__ deg,
                                                          int* __restrict__ out,
                                                          int* __restrict__ blk,
                                                          float* __restrict__ dinv, int n) {
    __shared__ int s[256];
    int tid = threadIdx.x;
    int i = blockIdx.x * 256 + tid;
    int v = (i < n) ? deg[i] : 0;
    if (i < n) dinv[i] = rsqrtf((float)(v + 1));  // +1 self loop
    s[tid] = v;
    __syncthreads();
    for (int off = 1; off < 256; off <<= 1) {
        int t = (tid >= off) ? s[tid - off] : 0;
        __syncthreads();
        s[tid] += t;
        __syncthreads();
    }
    if (i < n) out[i] = s[tid] - v;
    if (tid == 255) blk[blockIdx.x] = s[255];
}

__global__ __launch_bounds__(256) void scan_sums_kernel(int* __restrict__ blk, int nb,
                                                        int* __restrict__ row_ptr, int n) {
    __shared__ int s[256];
    int tid = threadIdx.x;
    int v = (tid < nb) ? blk[tid] : 0;
    s[tid] = v;
    __syncthreads();
    for (int off = 1; off < 256; off <<= 1) {
        int t = (tid >= off) ? s[tid - off] : 0;
        __syncthreads();
        s[tid] += t;
        __syncthreads();
    }
    if (tid < nb) blk[tid] = s[tid] - v;
    if (tid == 255) row_ptr[n] = s[255];
}

__global__ __launch_bounds__(256) void scan_add_kernel(int* __restrict__ row_ptr,
                                                       const int* __restrict__ blk,
                                                       int* __restrict__ cursor, int n) {
    int i = blockIdx.x * 256 + threadIdx.x;
    if (i < n) {
        int r = row_ptr[i] + blk[blockIdx.x];
        row_ptr[i] = r;
        cursor[i] = r;
    }
}

__global__ __launch_bounds__(256) void scatter_kernel(const int* __restrict__ src,
                                                      const int* __restrict__ dst,
                                                      int* __restrict__ cursor,
                                                      int* __restrict__ col_src) {
    int e = blockIdx.x * 256 + threadIdx.x;
    if (e < NE) {
        int d = dst[e];
        int pos = atomicAdd(&cursor[d], 1);
        col_src[pos] = src[e];
    }
}

// ---- fused weight split+transpose for W2..W5: W[K][Nd] fp32 -> hi/lo [Nd][K] bf16 ----

__global__ __launch_bounds__(256) void split_all_kernel(
    const float* __restrict__ W2, const float* __restrict__ W3,
    const float* __restrict__ W4, const float* __restrict__ W5,
    ushort* __restrict__ W2th, ushort* __restrict__ W2tl,
    ushort* __restrict__ W3th, ushort* __restrict__ W3tl,
    ushort* __restrict__ W4th, ushort* __restrict__ W4tl,
    ushort* __restrict__ W5th, ushort* __restrict__ W5tl) {
    int i = blockIdx.x * 256 + threadIdx.x;
    const float* W; ushort* Wth; ushort* Wtl; int K, Nd, idx;
    if (i < 16384) {                     // W2: 64x256
        W = W2; Wth = W2th; Wtl = W2tl; K = 64; Nd = 256; idx = i;
    } else if (i < 147456) {             // W3: 256x512
        W = W3; Wth = W3th; Wtl = W3tl; K = 256; Nd = 512; idx = i - 16384;
    } else if (i < 278528) {             // W4: 512x256
        W = W4; Wth = W4th; Wtl = W4tl; K = 512; Nd = 256; idx = i - 147456;
    } else if (i < 294912) {             // W5: 256x64
        W = W5; Wth = W5th; Wtl = W5tl; K = 256; Nd = 64; idx = i - 278528;
    } else {
        return;
    }
    int k = idx / Nd, n = idx - k * Nd;
    float w = W[idx];
    ushort h = f2bf(w);
    Wth[(size_t)n * K + k] = h;
    Wtl[(size_t)n * K + k] = f2bf(w - bf2f(h));
}

// ------- aggregation: out[v] = dv*sum du*H[u] + dv^2*H[v] (+bias,relu | hilo) -------
// vectorized: GS = WD/4 lanes/node, one float4 per lane, 8-deep gather prefetch.
// WD=256 -> GS=64 (1 node/wave), WD=64 -> GS=16, WD=16 -> GS=4.

template <int WD, bool BIAS, bool RELU, bool HILO>
__global__ __launch_bounds__(256) void aggregate_vec_kernel(
    const float* __restrict__ H, const float* __restrict__ dinv,
    const int* __restrict__ row_ptr, const int* __restrict__ col_src,
    const float* __restrict__ bias, float* __restrict__ out,
    ushort* __restrict__ oh, ushort* __restrict__ ol) {
    const int GS = WD / 4;
    const int NPB = 256 / GS;
    int v = blockIdx.x * NPB + (threadIdx.x / GS);
    int lg = threadIdx.x & (GS - 1);
    if (v >= NN) return;
    const float4* Hv = (const float4*)H;
    float dv = dinv[v];
    int beg = row_ptr[v], end = row_ptr[v + 1];
    float4 self = Hv[(size_t)v * GS + lg];
    float4 acc = make_float4(0.f, 0.f, 0.f, 0.f);
    for (int cbeg = beg; cbeg < end; cbeg += GS) {
        int cnt = min(GS, end - cbeg);
        int u_l = (lg < cnt) ? col_src[cbeg + lg] : 0;
        float w_l = (lg < cnt) ? dinv[u_l] : 0.0f;
        int e = 0;
        for (; e + 8 <= cnt; e += 8) {
            int u[8]; float w[8]; float4 h[8];
#pragma unroll
            for (int t = 0; t < 8; ++t) {
                u[t] = __shfl(u_l, e + t, GS);
                w[t] = __shfl(w_l, e + t, GS);
            }
#pragma unroll
            for (int t = 0; t < 8; ++t) h[t] = Hv[(size_t)u[t] * GS + lg];
#pragma unroll
            for (int t = 0; t < 8; ++t) {
                acc.x = fmaf(w[t], h[t].x, acc.x); acc.y = fmaf(w[t], h[t].y, acc.y);
                acc.z = fmaf(w[t], h[t].z, acc.z); acc.w = fmaf(w[t], h[t].w, acc.w);
            }
        }
        for (; e + 4 <= cnt; e += 4) {
            int u[4]; float w[4]; float4 h[4];
#pragma unroll
            for (int t = 0; t < 4; ++t) {
                u[t] = __shfl(u_l, e + t, GS);
                w[t] = __shfl(w_l, e + t, GS);
            }
#pragma unroll
            for (int t = 0; t < 4; ++t) h[t] = Hv[(size_t)u[t] * GS + lg];
#pragma unroll
            for (int t = 0; t < 4; ++t) {
                acc.x = fmaf(w[t], h[t].x, acc.x); acc.y = fmaf(w[t], h[t].y, acc.y);
                acc.z = fmaf(w[t], h[t].z, acc.z); acc.w = fmaf(w[t], h[t].w, acc.w);
            }
        }
        for (; e < cnt; ++e) {
            int u = __shfl(u_l, e, GS);
            float w = __shfl(w_l, e, GS);
            float4 h = Hv[(size_t)u * GS + lg];
            acc.x = fmaf(w, h.x, acc.x); acc.y = fmaf(w, h.y, acc.y);
            acc.z = fmaf(w, h.z, acc.z); acc.w = fmaf(w, h.w, acc.w);
        }
    }
    float dv2 = dv * dv;
    float4 r;
    r.x = fmaf(dv, acc.x, dv2 * self.x);
    r.y = fmaf(dv, acc.y, dv2 * self.y);
    r.z = fmaf(dv, acc.z, dv2 * self.z);
    r.w = fmaf(dv, acc.w, dv2 * self.w);
    if (BIAS) {
        float4 b = ((const float4*)bias)[lg];
        r.x += b.x; r.y += b.y; r.z += b.z; r.w += b.w;
    }
    if (RELU) {
        r.x = fmaxf(r.x, 0.f); r.y = fmaxf(r.y, 0.f);
        r.z = fmaxf(r.z, 0.f); r.w = fmaxf(r.w, 0.f);
    }
    if (HILO) {
        ushort4 hv, lv;
        hv.x = f2bf(r.x); lv.x = f2bf(r.x - bf2f(hv.x));
        hv.y = f2bf(r.y); lv.y = f2bf(r.y - bf2f(hv.y));
        hv.z = f2bf(r.z); lv.z = f2bf(r.z - bf2f(hv.z));
        hv.w = f2bf(r.w); lv.w = f2bf(r.w - bf2f(hv.w));
        *(ushort4*)&oh[(size_t)v * WD + lg * 4] = hv;
        *(ushort4*)&ol[(size_t)v * WD + lg * 4] = lv;
    } else {
        ((float4*)out)[(size_t)v * GS + lg] = r;
    }
}

// ---------------- split-bf16 MFMA GEMM (32x32x16): C = A @ Wt^T ----------
// 128x128 tile, 4 waves in 2x2, each wave 2x2 of 32x32x16 MFMA tiles.
// fp32 emulated via 3 MFMAs per k-half: hi*hi + lo*hi + hi*lo.
// C/D layout (m74/m101 verified): col=lane&31, row=(reg&3)+8*(reg>>2)+4*(lane>>5).
// EPI: 0 = fp32 out; 1 = fp32 bias+relu; 2 = bf16 hi/lo out, bias+relu.

template <int EPI>
__global__ __launch_bounds__(256, 2) void gemm_bf16x3_32_kernel(
    const ushort* __restrict__ Ah, const ushort* __restrict__ Al,
    const ushort* __restrict__ Bh, const ushort* __restrict__ Bl,
    const float* __restrict__ bias, float* __restrict__ Cf,
    ushort* __restrict__ Ch, ushort* __restrict__ Cl,
    int M, int K, int Nd) {
    __shared__ short At[2][128][40];
    __shared__ short Bt[2][128][40];
    int tid = threadIdx.x;
    int bm = blockIdx.y * 128, bn = blockIdx.x * 128;
    int lane = tid & 63;
    int wave = tid >> 6;
    int l31 = lane & 31, q2 = lane >> 5;  // 0/1
    int wm = (wave & 1) * 64, wn = (wave >> 1) * 64;
    int sr = tid >> 1, sc = (tid & 1) * 16;  // staging: row, 16-short half

    f32x16 acc[2][2];
#pragma unroll
    for (int i = 0; i < 2; ++i)
#pragma unroll
        for (int j = 0; j < 2; ++j)
#pragma unroll
            for (int r = 0; r < 16; ++r) acc[i][j][r] = 0.0f;

    bool arow_ok = (bm + sr) < M;
    bool brow_ok = (bn + sr) < Nd;
    const ushort* Aph = Ah + (size_t)(bm + sr) * K + sc;
    const ushort* Apl = Al + (size_t)(bm + sr) * K + sc;
    const ushort* Bph = Bh + (size_t)(bn + sr) * K + sc;
    const ushort* Bpl = Bl + (size_t)(bn + sr) * K + sc;

    for (int k0 = 0; k0 < K; k0 += 32) {
        int4 z = {0, 0, 0, 0};
        int4 vah0 = z, vah1 = z, val0 = z, val1 = z;
        if (arow_ok) {
            vah0 = *(const int4*)(Aph + k0);
            vah1 = *(const int4*)(Aph + k0 + 8);
            val0 = *(const int4*)(Apl + k0);
            val1 = *(const int4*)(Apl + k0 + 8);
        }
        int4 vbh0 = z, vbh1 = z, vbl0 = z, vbl1 = z;
        if (brow_ok) {
            vbh0 = *(const int4*)(Bph + k0);
            vbh1 = *(const int4*)(Bph + k0 + 8);
            vbl0 = *(const int4*)(Bpl + k0);
            vbl1 = *(const int4*)(Bpl + k0 + 8);
        }
        __syncthreads();
        *(int4*)&At[0][sr][sc] = vah0;
        *(int4*)&At[0][sr][sc + 8] = vah1;
        *(int4*)&At[1][sr][sc] = val0;
        *(int4*)&At[1][sr][sc + 8] = val1;
        *(int4*)&Bt[0][sr][sc] = vbh0;
        *(int4*)&Bt[0][sr][sc + 8] = vbh1;
        *(int4*)&Bt[1][sr][sc] = vbl0;
        *(int4*)&Bt[1][sr][sc + 8] = vbl1;
        __syncthreads();

        bf16x8 ah[2][2], al[2][2];
#pragma unroll
        for (int i = 0; i < 2; ++i) {
            const short* ar = &At[0][wm + i * 32 + l31][0];
            const short* arl = &At[1][wm + i * 32 + l31][0];
            ah[i][0] = *(const bf16x8*)(ar + q2 * 8);
            ah[i][1] = *(const bf16x8*)(ar + 16 + q2 * 8);
            al[i][0] = *(const bf16x8*)(arl + q2 * 8);
            al[i][1] = *(const bf16x8*)(arl + 16 + q2 * 8);
        }
#pragma unroll
        for (int j = 0; j < 2; ++j) {
            const short* br = &Bt[0][wn + j * 32 + l31][0];
            const short* brl = &Bt[1][wn + j * 32 + l31][0];
            bf16x8 bh0 = *(const bf16x8*)(br + q2 * 8);
            bf16x8 bh1 = *(const bf16x8*)(br + 16 + q2 * 8);
            bf16x8 bl0 = *(const bf16x8*)(brl + q2 * 8);
            bf16x8 bl1 = *(const bf16x8*)(brl + 16 + q2 * 8);
#pragma unroll
            for (int i = 0; i < 2; ++i) {
                acc[i][j] = __builtin_amdgcn_mfma_f32_32x32x16_bf16(ah[i][0], bh0, acc[i][j], 0, 0, 0);
                acc[i][j] = __builtin_amdgcn_mfma_f32_32x32x16_bf16(al[i][0], bh0, acc[i][j], 0, 0, 0);
                acc[i][j] = __builtin_amdgcn_mfma_f32_32x32x16_bf16(ah[i][0], bl0, acc[i][j], 0, 0, 0);
                acc[i][j] = __builtin_amdgcn_mfma_f32_32x32x16_bf16(ah[i][1], bh1, acc[i][j], 0, 0, 0);
                acc[i][j] = __builtin_amdgcn_mfma_f32_32x32x16_bf16(al[i][1], bh1, acc[i][j], 0, 0, 0);
                acc[i][j] = __builtin_amdgcn_mfma_f32_32x32x16_bf16(ah[i][1], bl1, acc[i][j], 0, 0, 0);
            }
        }
    }

    // epilogue: m = bm+wm+i*32+(r&3)+8*(r>>2)+4*q2, n = bn+wn+j*32+l31
#pragma unroll
    for (int j = 0; j < 2; ++j) {
        int n = bn + wn + j * 32 + l31;
        if (n >= Nd) continue;
        float bv = (EPI >= 1) ? bias[n] : 0.0f;
#pragma unroll
        for (int i = 0; i < 2; ++i) {
            int mb = bm + wm + i * 32 + 4 * q2;
#pragma unroll
            for (int r = 0; r < 16; ++r) {
                int m = mb + (r & 3) + 8 * (r >> 2);
                if (m >= M) continue;
                float v = acc[i][j][r];
                if (EPI >= 1) v = fmaxf(v + bv, 0.0f);
                if (EPI == 2) {
                    ushort h = f2bf(v);
                    Ch[(size_t)m * Nd + n] = h;
                    Cl[(size_t)m * Nd + n] = f2bf(v - bf2f(h));
                } else {
                    Cf[(size_t)m * Nd + n] = v;
                }
            }
        }
    }
}

// ---------------- fp32 GEMM, 64x64x16 tile, 4x4/thread (small layers) ----------------

template <bool BIASRELU>
__global__ __launch_bounds__(256, 4) void gemm_small_kernel(
    const float* __restrict__ A, const float* __restrict__ W,
    const float* __restrict__ bias, float* __restrict__ C,
    int M, int K, int Nd) {
    const int BK = 16;
    __shared__ float As[BK][68];
    __shared__ float Ws[BK][68];
    int bm = blockIdx.y * 64;
    int bn = blockIdx.x * 64;
    int tid = threadIdx.x;
    int tx = tid & 15;
    int ty = tid >> 4;

    int ar = tid >> 2;
    int ac = (tid & 3) * 4;
    int wcol = tid & 63;
    int wk0 = (tid >> 6) * 4;

    float acc[4][4];
#pragma unroll
    for (int i = 0; i < 4; ++i)
#pragma unroll
        for (int j = 0; j < 4; ++j) acc[i][j] = 0.0f;

    for (int k0 = 0; k0 < K; k0 += BK) {
        int gm = bm + ar;
        float a0 = 0.f, a1 = 0.f, a2 = 0.f, a3 = 0.f;
        if (gm < M) {
            const float* ap = &A[(size_t)gm * K];
            int gk = k0 + ac;
            a0 = (gk + 0 < K) ? ap[gk + 0] : 0.f;
            a1 = (gk + 1 < K) ? ap[gk + 1] : 0.f;
            a2 = (gk + 2 < K) ? ap[gk + 2] : 0.f;
            a3 = (gk + 3 < K) ? ap[gk + 3] : 0.f;
        }
        float w0 = 0.f, w1 = 0.f, w2 = 0.f, w3 = 0.f;
        if (bn + wcol < Nd) {
            int gk = k0 + wk0;
            w0 = (gk + 0 < K) ? W[(size_t)(gk + 0) * Nd + bn + wcol] : 0.f;
            w1 = (gk + 1 < K) ? W[(size_t)(gk + 1) * Nd + bn + wcol] : 0.f;
            w2 = (gk + 2 < K) ? W[(size_t)(gk + 2) * Nd + bn + wcol] : 0.f;
            w3 = (gk + 3 < K) ? W[(size_t)(gk + 3) * Nd + bn + wcol] : 0.f;
        }
        __syncthreads();
        As[ac + 0][ar] = a0;
        As[ac + 1][ar] = a1;
        As[ac + 2][ar] = a2;
        As[ac + 3][ar] = a3;
        Ws[wk0 + 0][wcol] = w0;
        Ws[wk0 + 1][wcol] = w1;
        Ws[wk0 + 2][wcol] = w2;
        Ws[wk0 + 3][wcol] = w3;
        __syncthreads();
#pragma unroll
        for (int kk = 0; kk < BK; ++kk) {
            float4 a = *(const float4*)&As[kk][ty * 4];
            float4 b = *(const float4*)&Ws[kk][tx * 4];
            float af[4] = {a.x, a.y, a.z, a.w};
            float bf[4] = {b.x, b.y, b.z, b.w};
#pragma unroll
            for (int i = 0; i < 4; ++i)
#pragma unroll
                for (int j = 0; j < 4; ++j) acc[i][j] = fmaf(af[i], bf[j], acc[i][j]);
        }
    }

    int col = bn + tx * 4;
    if (col >= Nd) return;
    float4 bi = make_float4(0.f, 0.f, 0.f, 0.f);
    if (BIASRELU) bi = *(const float4*)&bias[col];
#pragma unroll
    for (int i = 0; i < 4; ++i) {
        int m = bm + ty * 4 + i;
        if (m >= M) continue;
        float4 r = make_float4(acc[i][0], acc[i][1], acc[i][2], acc[i][3]);
        if (BIASRELU) {
            r.x = fmaxf(r.x + bi.x, 0.f); r.y = fmaxf(r.y + bi.y, 0.f);
            r.z = fmaxf(r.z + bi.z, 0.f); r.w = fmaxf(r.w + bi.w, 0.f);
        }
        *(float4*)&C[(size_t)m * Nd + col] = r;
    }
}

// ---------------- launch ----------------

extern "C" void kernel_launch(void* const* d_in, const int* in_sizes, int n_in,
                              void* d_out, int out_size, void* d_ws, size_t ws_size,
                              hipStream_t stream) {
    const float* x = (const float*)d_in[0];
    const int* ei = (const int*)d_in[1];
    const int* e_src = ei;
    const int* e_dst = ei + NE;
    const float* W1 = (const float*)d_in[2];
    const float* b1 = (const float*)d_in[3];
    const float* W2 = (const float*)d_in[4];
    const float* b2 = (const float*)d_in[5];
    const float* W3 = (const float*)d_in[6];
    const float* b3 = (const float*)d_in[7];
    const float* W4 = (const float*)d_in[8];
    const float* b4 = (const float*)d_in[9];
    const float* W5 = (const float*)d_in[10];
    const float* b5 = (const float*)d_in[11];
    const float* W6 = (const float*)d_in[12];
    const float* b6 = (const float*)d_in[13];
    float* out = (float*)d_out;

    // ---- workspace layout: 256B-aligned regions, liveness-checked ping-pong ----
    char* p = (char*)d_ws;
    auto take = [&p](size_t nbytes) {
        char* q = p;
        p += (nbytes + 255) & ~(size_t)255;
        return q;
    };
    char* RA = take((size_t)NN * 1024);   // 1 KB/node
    char* RB = take((size_t)NN * 1024);   // 1 KB/node
    char* RC = take((size_t)NN * 2048);   // 2 KB/node (X3 hi+lo @512)
    float* dinv = (float*)take((size_t)NN * 4);
    int* deg = (int*)take((size_t)NN * 4);
    int* row_ptr = (int*)take((size_t)(NN + 1) * 4);
    int* cursor = (int*)take((size_t)NN * 4);
    int* col_src = (int*)take((size_t)NE * 4);
    int* blk = (int*)take(256 * 4);
    ushort* W2th = (ushort*)take((size_t)64 * 256 * 2);
    ushort* W2tl = (ushort*)take((size_t)64 * 256 * 2);
    ushort* W3th = (ushort*)take((size_t)256 * 512 * 2);
    ushort* W3tl = (ushort*)take((size_t)256 * 512 * 2);
    ushort* W4th = (ushort*)take((size_t)512 * 256 * 2);
    ushort* W4tl = (ushort*)take((size_t)512 * 256 * 2);
    ushort* W5th = (ushort*)take((size_t)256 * 64 * 2);
    ushort* W5tl = (ushort*)take((size_t)256 * 64 * 2);

    // Buffer timeline (reads left, writes right; no overlap within a dispatch):
    //   L1g:  x        -> H1f (RA)     [x @ W1, no bias]
    //   agg1: H1f (RA) -> X1f (RB)     [S*H1+b1, relu]
    //   agg2: X1f (RB) -> A2  (RC)     [S*X1, hilo]
    //   L2 :  A2  (RC) -> X2f (RA)
    //   agg3: X2f (RA) -> A3  (RB)
    //   L3 :  A3  (RB) -> X3  (RC)
    //   L4 :  X3  (RC) -> H4f (RA)
    //   agg4: H4f (RA) -> X4 hi/lo (RB)
    //   L5 :  X4  (RB) -> H5f (RA)
    //   agg5: H5f (RA) -> X5f (RB)
    //   L6 :  X5f (RB) -> H6f (RA)
    //   agg6: H6f (RA) -> out
    float* H1f = (float*)RA;                       // NN x 64
    float* X1f = (float*)RB;                       // NN x 64
    ushort* A2h = (ushort*)RC;                     // NN x 64
    ushort* A2l = A2h + (size_t)NN * 64;
    float* X2f = (float*)RA;                       // NN x 256
    ushort* A3h = (ushort*)RB;                     // NN x 256
    ushort* A3l = A3h + (size_t)NN * 256;
    ushort* X3h = (ushort*)RC;                     // NN x 512
    ushort* X3l = X3h + (size_t)NN * 512;
    float* H4f = (float*)RA;                       // NN x 256
    ushort* X4h = (ushort*)RB;                     // NN x 256
    ushort* X4l = X4h + (size_t)NN * 256;
    float* H5f = (float*)RA;                       // NN x 64
    float* X5f = (float*)RB;                       // NN x 64
    float* H6f = (float*)RA;                       // NN x 16

    const int nblkN = (NN + 255) / 256;
    const int nblkE = (NE + 255) / 256;

    // CSR build
    zero_int_kernel<<<nblkN, 256, 0, stream>>>(deg, NN);
    count_deg_kernel<<<nblkE, 256, 0, stream>>>(e_dst, deg);
    scan_blocks_kernel<<<nblkN, 256, 0, stream>>>(deg, row_ptr, blk, dinv, NN);
    scan_sums_kernel<<<1, 256, 0, stream>>>(blk, nblkN, row_ptr, NN);
    scan_add_kernel<<<nblkN, 256, 0, stream>>>(row_ptr, blk, cursor, NN);
    scatter_kernel<<<nblkE, 256, 0, stream>>>(e_src, e_dst, cursor, col_src);

    // fused weight splits (W2,W3,W4,W5)
    split_all_kernel<<<(294912 + 255) / 256, 256, 0, stream>>>(
        W2, W3, W4, W5, W2th, W2tl, W3th, W3tl, W4th, W4tl, W5th, W5tl);

    const int aggGrid256 = (NN + 3) / 4;    // WD=256: 4 nodes/block
    const int aggGrid64v = (NN + 15) / 16;  // WD=64 vec: 16 nodes/block
    const int aggGrid16v = (NN + 63) / 64;  // WD=16 vec: 64 nodes/block
    const int mrows = (NN + 127) / 128;     // 391

    // L1 (GEMM-first): H1 = x@W1 ; X1 = relu(S*H1+b1)
    {
        dim3 g(1, (NN + 63) / 64);
        gemm_small_kernel<false><<<g, 256, 0, stream>>>(x, W1, nullptr, H1f, NN, 35, 64);
    }
    aggregate_vec_kernel<64, true, true, false><<<aggGrid64v, 256, 0, stream>>>(
        H1f, dinv, row_ptr, col_src, b1, X1f, nullptr, nullptr);
    // L2: agg(X1,64) -> A2 hi/lo ; X2 = relu(A2@W2+b2) -> X2f (256 f32)
    aggregate_vec_kernel<64, false, false, true><<<aggGrid64v, 256, 0, stream>>>(
        X1f, dinv, row_ptr, col_src, nullptr, nullptr, A2h, A2l);
    {
        dim3 g(2, mrows);
        gemm_bf16x3_32_kernel<1><<<g, 256, 0, stream>>>(A2h, A2l, W2th, W2tl, b2,
                                                        X2f, nullptr, nullptr, NN, 64, 256);
    }
    // L3: agg(X2,256) -> A3 hi/lo ; X3 = relu(A3@W3+b3) -> X3 hi/lo (512 bf16)
    aggregate_vec_kernel<256, false, false, true><<<aggGrid256, 256, 0, stream>>>(
        X2f, dinv, row_ptr, col_src, nullptr, nullptr, A3h, A3l);
    {
        dim3 g(4, mrows);
        gemm_bf16x3_32_kernel<2><<<g, 256, 0, stream>>>(A3h, A3l, W3th, W3tl, b3,
                                                        nullptr, X3h, X3l, NN, 256, 512);
    }
    // L4: H4 = X3@W4 -> H4f (256 f32) ; X4 = relu(S*H4+b4) -> X4 hi/lo (256 bf16)
    {
        dim3 g(2, mrows);
        gemm_bf16x3_32_kernel<0><<<g, 256, 0, stream>>>(X3h, X3l, W4th, W4tl, nullptr,
                                                        H4f, nullptr, nullptr, NN, 512, 256);
    }
    aggregate_vec_kernel<256, true, true, true><<<aggGrid256, 256, 0, stream>>>(
        H4f, dinv, row_ptr, col_src, b4, nullptr, X4h, X4l);
    // L5: H5 = X4@W5 -> H5f (64 f32) ; X5 = relu(S*H5+b5) -> X5f (64 f32)
    {
        dim3 g(1, mrows);
        gemm_bf16x3_32_kernel<0><<<g, 256, 0, stream>>>(X4h, X4l, W5th, W5tl, nullptr,
                                                        H5f, nullptr, nullptr, NN, 256, 64);
    }
    aggregate_vec_kernel<64, true, true, false><<<aggGrid64v, 256, 0, stream>>>(
        H5f, dinv, row_ptr, col_src, b5, X5f, nullptr, nullptr);
    // L6: H6 = X5@W6 -> H6f (16 f32) ; out = S*H6 + b6
    {
        dim3 g(1, (NN + 63) / 64);
        gemm_small_kernel<false><<<g, 256, 0, stream>>>(X5f, W6, nullptr, H6f, NN, 64, 16);
    }
    aggregate_vec_kernel<16, true, false, false><<<aggGrid16v, 256, 0, stream>>>(
        H6f, dinv, row_ptr, col_src, b6, out, nullptr, nullptr);
}